// Round 1
// baseline (502.213 us; speedup 1.0000x reference)
//
#include <hip/hip_runtime.h>
#include <hip/hip_bf16.h>

#define NNODES 30000
#define NEDGES 480000
#define TE (NEDGES + NNODES)   // edges incl. self-loops
#define FH 256                 // hidden width (H*C)
#define NH 8                   // heads

// ---------------- CSR build (dst-sorted src lists) ----------------
__global__ void count_kernel(const int* __restrict__ ei, int* __restrict__ counts) {
    int e = blockIdx.x * 256 + threadIdx.x;
    if (e >= TE) return;
    int d = (e < NEDGES) ? ei[NEDGES + e] : (e - NEDGES);
    atomicAdd(&counts[d], 1);
}

__global__ __launch_bounds__(1024) void scan_kernel(const int* __restrict__ counts,
                                                    int* __restrict__ rp,
                                                    int* __restrict__ cursor) {
    __shared__ int part[1024];
    const int tid = threadIdx.x;
    const int chunk = (NNODES + 1023) / 1024;   // 30
    int lo = tid * chunk, hi = min(lo + chunk, NNODES);
    int s = 0;
    for (int i = lo; i < hi; ++i) s += counts[i];
    part[tid] = s;
    __syncthreads();
    // Hillis-Steele inclusive scan
    for (int off = 1; off < 1024; off <<= 1) {
        int v = (tid >= off) ? part[tid - off] : 0;
        __syncthreads();
        part[tid] += v;
        __syncthreads();
    }
    int run = part[tid] - s;   // exclusive prefix
    for (int i = lo; i < hi; ++i) {
        rp[i] = run; cursor[i] = run;
        run += counts[i];
    }
    if (tid == 1023) rp[NNODES] = part[1023];
}

__global__ void fill_kernel(const int* __restrict__ ei, int* __restrict__ cursor,
                            int* __restrict__ ssrc) {
    int e = blockIdx.x * 256 + threadIdx.x;
    if (e >= TE) return;
    int s, d;
    if (e < NEDGES) { s = ei[e]; d = ei[NEDGES + e]; }
    else            { s = e - NEDGES; d = s; }
    int pos = atomicAdd(&cursor[d], 1);
    ssrc[pos] = s;
}

// ---------------- GEMM (h = X @ W) + fused per-head alpha dots ----------------
// 32 rows per block, 256 threads = one output column each. fp32 vector FMA.
template<int K>
__global__ __launch_bounds__(256) void gemm_alpha(
    const float* __restrict__ X, const float* __restrict__ W,
    const float* __restrict__ ASRC, const float* __restrict__ ADST,
    float* __restrict__ Hout, float* __restrict__ AS, float* __restrict__ AD) {

    __shared__ float xs[32][K];
    const int tid = threadIdx.x;
    const int row0 = blockIdx.x * 32;

    for (int r = 0; r < 32; ++r) {
        int row = row0 + r;
        for (int k = tid; k < K; k += 256)
            xs[r][k] = (row < NNODES) ? X[(size_t)row * K + k] : 0.f;
    }
    __syncthreads();

    float acc[32];
#pragma unroll
    for (int r = 0; r < 32; ++r) acc[r] = 0.f;

    for (int k = 0; k < K; k += 4) {
        float w0 = W[(size_t)(k + 0) * FH + tid];
        float w1 = W[(size_t)(k + 1) * FH + tid];
        float w2 = W[(size_t)(k + 2) * FH + tid];
        float w3 = W[(size_t)(k + 3) * FH + tid];
#pragma unroll
        for (int r = 0; r < 32; ++r) {
            float4 xv = *reinterpret_cast<const float4*>(&xs[r][k]);
            acc[r] = fmaf(xv.x, w0, acc[r]);
            acc[r] = fmaf(xv.y, w1, acc[r]);
            acc[r] = fmaf(xv.z, w2, acc[r]);
            acc[r] = fmaf(xv.w, w3, acc[r]);
        }
    }

    const float asw = ASRC[tid];
    const float adw = ADST[tid];
    const int head = tid >> 5;
#pragma unroll 1
    for (int r = 0; r < 32; ++r) {
        int row = row0 + r;
        if (row >= NNODES) break;          // uniform per block
        float v = acc[r];
        Hout[(size_t)row * FH + tid] = v;
        float ps = v * asw, pd = v * adw;
#pragma unroll
        for (int off = 16; off >= 1; off >>= 1) {
            ps += __shfl_xor(ps, off);
            pd += __shfl_xor(pd, off);
        }
        if ((tid & 31) == 0) {
            AS[row * NH + head] = ps;
            AD[row * NH + head] = pd;
        }
    }
}

// ---------------- Per-node gather aggregation (segment softmax + weighted sum) ----------------
// One block per destination node. Unnormalized aggregate: out = sum(w*h[src]) / sum(w).
template<bool FINAL>
__global__ __launch_bounds__(256) void aggregate(
    const float* __restrict__ HF, const float* __restrict__ AS, const float* __restrict__ AD,
    const int* __restrict__ rp, const int* __restrict__ ssrc,
    const float* __restrict__ BIAS,
    float* __restrict__ XOUT,
    const float* __restrict__ WL, const float* __restrict__ BL,
    float* __restrict__ OUT) {

    const int i   = blockIdx.x;
    const int tid = threadIdx.x;
    const int h   = tid >> 5;     // head for channel-ownership (tid = h*32+c)
    const int hh  = tid & 7;      // head for (edge,head) work items
    const int wid = tid >> 6;

    __shared__ float ad_l[8], maxl[8], den_l[8];
    __shared__ float red[4][8];
    __shared__ int   src_l[128];
    __shared__ float w_l[128][8];
    __shared__ float fin[4];

    if (tid < 8) ad_l[tid] = AD[i * NH + tid];
    __syncthreads();

    const int p0  = rp[i];
    const int deg = rp[i + 1] - p0;

    // ---- phase 1: per-head max of leaky_relu(as[src]+ad[dst]) ----
    float mx[8];
#pragma unroll
    for (int q = 0; q < 8; ++q) mx[q] = -1e30f;
    for (int e = tid; e < deg; e += 256) {
        int s = ssrc[p0 + e];
        const float* as = &AS[s * NH];
#pragma unroll
        for (int q = 0; q < 8; ++q) {
            float sv = as[q] + ad_l[q];
            sv = sv > 0.f ? sv : 0.2f * sv;
            mx[q] = fmaxf(mx[q], sv);
        }
    }
#pragma unroll
    for (int q = 0; q < 8; ++q) {
#pragma unroll
        for (int off = 32; off >= 1; off >>= 1)
            mx[q] = fmaxf(mx[q], __shfl_xor(mx[q], off));
    }
    if ((tid & 63) == 0) {
#pragma unroll
        for (int q = 0; q < 8; ++q) red[wid][q] = mx[q];
    }
    __syncthreads();
    if (tid < 8)
        maxl[tid] = fmaxf(fmaxf(red[0][tid], red[1][tid]), fmaxf(red[2][tid], red[3][tid]));
    // (first chunk-loop barrier orders maxl for all readers)

    // ---- phase 2: chunks of 128 edges: w = exp(s - max); aggregate ----
    float acc = 0.f, dpart = 0.f;
    for (int base = 0; base < deg; base += 128) {
        int ne = min(128, deg - base);
        __syncthreads();                      // protect src_l/w_l reuse; orders maxl
        if (tid < ne) src_l[tid] = ssrc[p0 + base + tid];
        __syncthreads();
        for (int it = tid; it < ne * NH; it += 256) {   // hh = tid&7 constant
            int e = it >> 3;
            int s = src_l[e];
            float sv = AS[s * NH + hh] + ad_l[hh];
            sv = sv > 0.f ? sv : 0.2f * sv;
            float w = __expf(sv - maxl[hh]);
            w_l[e][hh] = w;
            dpart += w;
        }
        __syncthreads();
        for (int e = 0; e < ne; ++e) {
            acc = fmaf(w_l[e][h], HF[(size_t)src_l[e] * FH + tid], acc);
        }
    }

    // ---- denominator reduce (lanes with same tid&7) ----
    dpart += __shfl_xor(dpart, 8);
    dpart += __shfl_xor(dpart, 16);
    dpart += __shfl_xor(dpart, 32);
    __syncthreads();
    if ((tid & 63) < 8) red[wid][tid & 7] = dpart;
    __syncthreads();
    if (tid < 8) den_l[tid] = red[0][tid] + red[1][tid] + red[2][tid] + red[3][tid];
    __syncthreads();

    // ---- epilogue: normalize + bias + ELU (+ fused final linear) ----
    float val = acc / (den_l[h] + 1e-16f) + BIAS[tid];
    float o = val > 0.f ? val : expm1f(val);
    if (!FINAL) {
        XOUT[(size_t)i * FH + tid] = o;
    } else {
        float pl = o * WL[tid];
#pragma unroll
        for (int off = 32; off >= 1; off >>= 1) pl += __shfl_xor(pl, off);
        if ((tid & 63) == 0) fin[wid] = pl;
        __syncthreads();
        if (tid == 0) OUT[i] = fin[0] + fin[1] + fin[2] + fin[3] + BL[0];
    }
}

// ---------------- launch ----------------
extern "C" void kernel_launch(void* const* d_in, const int* in_sizes, int n_in,
                              void* d_out, int out_size, void* d_ws, size_t ws_size,
                              hipStream_t stream) {
    const float* x   = (const float*)d_in[0];
    const int*   ei  = (const int*)d_in[1];
    const float* W1  = (const float*)d_in[2];
    const float* a1s = (const float*)d_in[3];
    const float* a1d = (const float*)d_in[4];
    const float* b1  = (const float*)d_in[5];
    const float* W2  = (const float*)d_in[6];
    const float* a2s = (const float*)d_in[7];
    const float* a2d = (const float*)d_in[8];
    const float* b2  = (const float*)d_in[9];
    const float* Wl  = (const float*)d_in[10];
    const float* bl  = (const float*)d_in[11];
    float* out = (float*)d_out;

    char* w = (char*)d_ws;
    auto alloc = [&](size_t bytes) -> char* {
        char* p = w;
        w += (bytes + 255) & ~size_t(255);
        return p;
    };
    int*   counts = (int*)alloc((size_t)NNODES * 4);
    int*   rp     = (int*)alloc((size_t)(NNODES + 1) * 4);
    int*   cursor = (int*)alloc((size_t)NNODES * 4);
    int*   ssrc   = (int*)alloc((size_t)TE * 4);
    float* hlin   = (float*)alloc((size_t)NNODES * FH * 4);
    float* x2     = (float*)alloc((size_t)NNODES * FH * 4);
    float* asb    = (float*)alloc((size_t)NNODES * NH * 4);
    float* adb    = (float*)alloc((size_t)NNODES * NH * 4);

    hipMemsetAsync(counts, 0, (size_t)NNODES * 4, stream);
    count_kernel<<<(TE + 255) / 256, 256, 0, stream>>>(ei, counts);
    scan_kernel<<<1, 1024, 0, stream>>>(counts, rp, cursor);
    fill_kernel<<<(TE + 255) / 256, 256, 0, stream>>>(ei, cursor, ssrc);

    const int gblocks = (NNODES + 31) / 32;
    gemm_alpha<128><<<gblocks, 256, 0, stream>>>(x, W1, a1s, a1d, hlin, asb, adb);
    aggregate<false><<<NNODES, 256, 0, stream>>>(hlin, asb, adb, rp, ssrc, b1, x2,
                                                 nullptr, nullptr, nullptr);
    gemm_alpha<256><<<gblocks, 256, 0, stream>>>(x2, W2, a2s, a2d, hlin, asb, adb);
    aggregate<true><<<NNODES, 256, 0, stream>>>(hlin, asb, adb, rp, ssrc, b2, nullptr,
                                                Wl, bl, out);
}

// Round 2
// 415.339 us; speedup vs baseline: 1.2092x; 1.2092x over previous
//
#include <hip/hip_runtime.h>
#include <hip/hip_bf16.h>

#define NNODES 30000
#define NEDGES 480000
#define TE (NEDGES + NNODES)   // edges incl. self-loops
#define FH 256                 // hidden width (H*C)
#define NH 8                   // heads

// ---------------- CSR build (dst-sorted src lists) ----------------
__global__ void count_kernel(const int* __restrict__ ei, int* __restrict__ counts) {
    int e = blockIdx.x * 256 + threadIdx.x;
    if (e >= TE) return;
    int d = (e < NEDGES) ? ei[NEDGES + e] : (e - NEDGES);
    atomicAdd(&counts[d], 1);
}

__global__ __launch_bounds__(1024) void scan_kernel(const int* __restrict__ counts,
                                                    int* __restrict__ rp,
                                                    int* __restrict__ cursor) {
    __shared__ int part[1024];
    const int tid = threadIdx.x;
    const int chunk = (NNODES + 1023) / 1024;   // 30
    int lo = tid * chunk, hi = min(lo + chunk, NNODES);
    int s = 0;
    for (int i = lo; i < hi; ++i) s += counts[i];
    part[tid] = s;
    __syncthreads();
    // Hillis-Steele inclusive scan
    for (int off = 1; off < 1024; off <<= 1) {
        int v = (tid >= off) ? part[tid - off] : 0;
        __syncthreads();
        part[tid] += v;
        __syncthreads();
    }
    int run = part[tid] - s;   // exclusive prefix
    for (int i = lo; i < hi; ++i) {
        rp[i] = run; cursor[i] = run;
        run += counts[i];
    }
    if (tid == 1023) rp[NNODES] = part[1023];
}

__global__ void fill_kernel(const int* __restrict__ ei, int* __restrict__ cursor,
                            int* __restrict__ ssrc) {
    int e = blockIdx.x * 256 + threadIdx.x;
    if (e >= TE) return;
    int s, d;
    if (e < NEDGES) { s = ei[e]; d = ei[NEDGES + e]; }
    else            { s = e - NEDGES; d = s; }
    int pos = atomicAdd(&cursor[d], 1);
    ssrc[pos] = s;
}

// ---------------- Register-tiled fp32 GEMM (h = X @ W) + fused alpha dots ----
// BM=64 x BN=128 tile, BK=32, 256 threads, 8x4 micro-tile per thread.
// A staged k-major (As[k][m], stride 68 for bank spread + 16B align);
// B staged row-major (Bs[k][n], stride 132).
template<int K>
__global__ __launch_bounds__(256) void gemm_tile(
    const float* __restrict__ X, const float* __restrict__ W,
    const float* __restrict__ ASRC, const float* __restrict__ ADST,
    float* __restrict__ Hout, float* __restrict__ AS, float* __restrict__ AD) {

    constexpr int BM = 64, BN = 128, BK = 32;
    __shared__ float As[BK][68];    // 8.7 KB
    __shared__ float Bs[BK][132];   // 16.9 KB

    const int tid = threadIdx.x;
    const int tx  = tid & 31;        // 0..31 -> col group
    const int ty  = tid >> 5;        // 0..7  -> row group
    const int row0 = blockIdx.x * BM;
    const int col0 = blockIdx.y * BN;

    float acc[8][4];
#pragma unroll
    for (int i = 0; i < 8; ++i)
#pragma unroll
        for (int j = 0; j < 4; ++j) acc[i][j] = 0.f;

    for (int k0 = 0; k0 < K; k0 += BK) {
        // ---- stage A: 64 rows x 32 k, transposed into As[k][m] ----
#pragma unroll
        for (int j = 0; j < 2; ++j) {
            int idx = tid + 256 * j;          // 0..511
            int m   = idx >> 3;               // 0..63
            int kq  = (idx & 7) * 4;          // 0,4,..,28
            int gr  = row0 + m;
            float4 v = make_float4(0.f, 0.f, 0.f, 0.f);
            if (gr < NNODES)
                v = *reinterpret_cast<const float4*>(&X[(size_t)gr * K + k0 + kq]);
            As[kq + 0][m] = v.x;
            As[kq + 1][m] = v.y;
            As[kq + 2][m] = v.z;
            As[kq + 3][m] = v.w;
        }
        // ---- stage B: 32 k x 128 cols ----
#pragma unroll
        for (int j = 0; j < 4; ++j) {
            int idx = tid + 256 * j;          // 0..1023
            int kk  = idx >> 5;               // 0..31
            int cq  = (idx & 31) * 4;         // 0..124
            float4 v = *reinterpret_cast<const float4*>(&W[(size_t)(k0 + kk) * FH + col0 + cq]);
            *reinterpret_cast<float4*>(&Bs[kk][cq]) = v;
        }
        __syncthreads();

#pragma unroll 4
        for (int kk = 0; kk < BK; ++kk) {
            float4 a0 = *reinterpret_cast<const float4*>(&As[kk][ty * 8]);
            float4 a1 = *reinterpret_cast<const float4*>(&As[kk][ty * 8 + 4]);
            float4 b  = *reinterpret_cast<const float4*>(&Bs[kk][tx * 4]);
            float av[8] = {a0.x, a0.y, a0.z, a0.w, a1.x, a1.y, a1.z, a1.w};
#pragma unroll
            for (int i = 0; i < 8; ++i) {
                acc[i][0] = fmaf(av[i], b.x, acc[i][0]);
                acc[i][1] = fmaf(av[i], b.y, acc[i][1]);
                acc[i][2] = fmaf(av[i], b.z, acc[i][2]);
                acc[i][3] = fmaf(av[i], b.w, acc[i][3]);
            }
        }
        __syncthreads();
    }

    // ---- epilogue: store h + fused per-head alpha dot products ----
    const int col   = col0 + tx * 4;
    const int head  = tx >> 3;                // 0..3 within N-tile
    const int ghead = blockIdx.y * 4 + head;  // global head
    const float4 asw = *reinterpret_cast<const float4*>(&ASRC[col]);
    const float4 adw = *reinterpret_cast<const float4*>(&ADST[col]);

#pragma unroll
    for (int i = 0; i < 8; ++i) {
        int row = row0 + ty * 8 + i;
        if (row >= NNODES) break;     // uniform across the 8-lane reduce group
        float4 v = make_float4(acc[i][0], acc[i][1], acc[i][2], acc[i][3]);
        *reinterpret_cast<float4*>(&Hout[(size_t)row * FH + col]) = v;
        float ps = fmaf(v.x, asw.x, fmaf(v.y, asw.y, fmaf(v.z, asw.z, v.w * asw.w)));
        float pd = fmaf(v.x, adw.x, fmaf(v.y, adw.y, fmaf(v.z, adw.z, v.w * adw.w)));
#pragma unroll
        for (int off = 4; off >= 1; off >>= 1) {
            ps += __shfl_xor(ps, off);
            pd += __shfl_xor(pd, off);
        }
        if ((tx & 7) == 0) {
            AS[row * NH + ghead] = ps;
            AD[row * NH + ghead] = pd;
        }
    }
}

// ---------------- Per-node gather aggregation (segment softmax + weighted sum) ----------------
// One block per destination node. Unnormalized aggregate: out = sum(w*h[src]) / sum(w).
template<bool FINAL>
__global__ __launch_bounds__(256) void aggregate(
    const float* __restrict__ HF, const float* __restrict__ AS, const float* __restrict__ AD,
    const int* __restrict__ rp, const int* __restrict__ ssrc,
    const float* __restrict__ BIAS,
    float* __restrict__ XOUT,
    const float* __restrict__ WL, const float* __restrict__ BL,
    float* __restrict__ OUT) {

    const int i   = blockIdx.x;
    const int tid = threadIdx.x;
    const int h   = tid >> 5;     // head for channel-ownership (tid = h*32+c)
    const int hh  = tid & 7;      // head for (edge,head) work items
    const int wid = tid >> 6;

    __shared__ float ad_l[8], maxl[8], den_l[8];
    __shared__ float red[4][8];
    __shared__ int   src_l[128];
    __shared__ float w_l[128][8];
    __shared__ float fin[4];

    if (tid < 8) ad_l[tid] = AD[i * NH + tid];
    __syncthreads();

    const int p0  = rp[i];
    const int deg = rp[i + 1] - p0;

    // ---- phase 1: per-head max of leaky_relu(as[src]+ad[dst]) ----
    float mx[8];
#pragma unroll
    for (int q = 0; q < 8; ++q) mx[q] = -1e30f;
    for (int e = tid; e < deg; e += 256) {
        int s = ssrc[p0 + e];
        const float* as = &AS[s * NH];
#pragma unroll
        for (int q = 0; q < 8; ++q) {
            float sv = as[q] + ad_l[q];
            sv = sv > 0.f ? sv : 0.2f * sv;
            mx[q] = fmaxf(mx[q], sv);
        }
    }
#pragma unroll
    for (int q = 0; q < 8; ++q) {
#pragma unroll
        for (int off = 32; off >= 1; off >>= 1)
            mx[q] = fmaxf(mx[q], __shfl_xor(mx[q], off));
    }
    if ((tid & 63) == 0) {
#pragma unroll
        for (int q = 0; q < 8; ++q) red[wid][q] = mx[q];
    }
    __syncthreads();
    if (tid < 8)
        maxl[tid] = fmaxf(fmaxf(red[0][tid], red[1][tid]), fmaxf(red[2][tid], red[3][tid]));
    // (first chunk-loop barrier orders maxl for all readers)

    // ---- phase 2: chunks of 128 edges: w = exp(s - max); aggregate ----
    float acc = 0.f, dpart = 0.f;
    for (int base = 0; base < deg; base += 128) {
        int ne = min(128, deg - base);
        __syncthreads();                      // protect src_l/w_l reuse; orders maxl
        if (tid < ne) src_l[tid] = ssrc[p0 + base + tid];
        __syncthreads();
        for (int it = tid; it < ne * NH; it += 256) {   // hh = tid&7 constant
            int e = it >> 3;
            int s = src_l[e];
            float sv = AS[s * NH + hh] + ad_l[hh];
            sv = sv > 0.f ? sv : 0.2f * sv;
            float w = __expf(sv - maxl[hh]);
            w_l[e][hh] = w;
            dpart += w;
        }
        __syncthreads();
        for (int e = 0; e < ne; ++e) {
            acc = fmaf(w_l[e][h], HF[(size_t)src_l[e] * FH + tid], acc);
        }
    }

    // ---- denominator reduce (lanes with same tid&7) ----
    dpart += __shfl_xor(dpart, 8);
    dpart += __shfl_xor(dpart, 16);
    dpart += __shfl_xor(dpart, 32);
    __syncthreads();
    if ((tid & 63) < 8) red[wid][tid & 7] = dpart;
    __syncthreads();
    if (tid < 8) den_l[tid] = red[0][tid] + red[1][tid] + red[2][tid] + red[3][tid];
    __syncthreads();

    // ---- epilogue: normalize + bias + ELU (+ fused final linear) ----
    float val = acc / (den_l[h] + 1e-16f) + BIAS[tid];
    float o = val > 0.f ? val : expm1f(val);
    if (!FINAL) {
        XOUT[(size_t)i * FH + tid] = o;
    } else {
        float pl = o * WL[tid];
#pragma unroll
        for (int off = 32; off >= 1; off >>= 1) pl += __shfl_xor(pl, off);
        if ((tid & 63) == 0) fin[wid] = pl;
        __syncthreads();
        if (tid == 0) OUT[i] = fin[0] + fin[1] + fin[2] + fin[3] + BL[0];
    }
}

// ---------------- launch ----------------
extern "C" void kernel_launch(void* const* d_in, const int* in_sizes, int n_in,
                              void* d_out, int out_size, void* d_ws, size_t ws_size,
                              hipStream_t stream) {
    const float* x   = (const float*)d_in[0];
    const int*   ei  = (const int*)d_in[1];
    const float* W1  = (const float*)d_in[2];
    const float* a1s = (const float*)d_in[3];
    const float* a1d = (const float*)d_in[4];
    const float* b1  = (const float*)d_in[5];
    const float* W2  = (const float*)d_in[6];
    const float* a2s = (const float*)d_in[7];
    const float* a2d = (const float*)d_in[8];
    const float* b2  = (const float*)d_in[9];
    const float* Wl  = (const float*)d_in[10];
    const float* bl  = (const float*)d_in[11];
    float* out = (float*)d_out;

    char* w = (char*)d_ws;
    auto alloc = [&](size_t bytes) -> char* {
        char* p = w;
        w += (bytes + 255) & ~size_t(255);
        return p;
    };
    int*   counts = (int*)alloc((size_t)NNODES * 4);
    int*   rp     = (int*)alloc((size_t)(NNODES + 1) * 4);
    int*   cursor = (int*)alloc((size_t)NNODES * 4);
    int*   ssrc   = (int*)alloc((size_t)TE * 4);
    float* hlin   = (float*)alloc((size_t)NNODES * FH * 4);
    float* x2     = (float*)alloc((size_t)NNODES * FH * 4);
    float* asb    = (float*)alloc((size_t)NNODES * NH * 4);
    float* adb    = (float*)alloc((size_t)NNODES * NH * 4);

    hipMemsetAsync(counts, 0, (size_t)NNODES * 4, stream);
    count_kernel<<<(TE + 255) / 256, 256, 0, stream>>>(ei, counts);
    scan_kernel<<<1, 1024, 0, stream>>>(counts, rp, cursor);
    fill_kernel<<<(TE + 255) / 256, 256, 0, stream>>>(ei, cursor, ssrc);

    const dim3 ggrid((NNODES + 63) / 64, FH / 128);
    gemm_tile<128><<<ggrid, 256, 0, stream>>>(x, W1, a1s, a1d, hlin, asb, adb);
    aggregate<false><<<NNODES, 256, 0, stream>>>(hlin, asb, adb, rp, ssrc, b1, x2,
                                                 nullptr, nullptr, nullptr);
    gemm_tile<256><<<ggrid, 256, 0, stream>>>(x2, W2, a2s, a2d, hlin, asb, adb);
    aggregate<true><<<NNODES, 256, 0, stream>>>(hlin, asb, adb, rp, ssrc, b2, nullptr,
                                                Wl, bl, out);
}

// Round 3
// 354.212 us; speedup vs baseline: 1.4178x; 1.1726x over previous
//
#include <hip/hip_runtime.h>
#include <hip/hip_bf16.h>

#define NNODES 30000
#define NEDGES 480000
#define TE (NEDGES + NNODES)   // edges incl. self-loops
#define FH 256                 // hidden width (H*C)
#define NH 8                   // heads

// ---------------- CSR build (dst-sorted src lists) ----------------
__global__ void count_kernel(const int* __restrict__ ei, int* __restrict__ counts) {
    int e = blockIdx.x * 256 + threadIdx.x;
    if (e >= TE) return;
    int d = (e < NEDGES) ? ei[NEDGES + e] : (e - NEDGES);
    atomicAdd(&counts[d], 1);
}

__global__ __launch_bounds__(1024) void scan_kernel(const int* __restrict__ counts,
                                                    int* __restrict__ rp,
                                                    int* __restrict__ cursor) {
    __shared__ int part[1024];
    const int tid = threadIdx.x;
    const int chunk = (NNODES + 1023) / 1024;   // 30
    int lo = tid * chunk, hi = min(lo + chunk, NNODES);
    int s = 0;
    for (int i = lo; i < hi; ++i) s += counts[i];
    part[tid] = s;
    __syncthreads();
    // Hillis-Steele inclusive scan
    for (int off = 1; off < 1024; off <<= 1) {
        int v = (tid >= off) ? part[tid - off] : 0;
        __syncthreads();
        part[tid] += v;
        __syncthreads();
    }
    int run = part[tid] - s;   // exclusive prefix
    for (int i = lo; i < hi; ++i) {
        rp[i] = run; cursor[i] = run;
        run += counts[i];
    }
    if (tid == 1023) rp[NNODES] = part[1023];
}

__global__ void fill_kernel(const int* __restrict__ ei, int* __restrict__ cursor,
                            int* __restrict__ ssrc) {
    int e = blockIdx.x * 256 + threadIdx.x;
    if (e >= TE) return;
    int s, d;
    if (e < NEDGES) { s = ei[e]; d = ei[NEDGES + e]; }
    else            { s = e - NEDGES; d = s; }
    int pos = atomicAdd(&cursor[d], 1);
    ssrc[pos] = s;
}

// ---------------- Register-tiled fp32 GEMM (h = X @ W) + fused alpha dots ----
// BM=64 x BN=128 tile, BK=32, 256 threads, 8x4 micro-tile per thread.
template<int K>
__global__ __launch_bounds__(256) void gemm_tile(
    const float* __restrict__ X, const float* __restrict__ W,
    const float* __restrict__ ASRC, const float* __restrict__ ADST,
    float* __restrict__ Hout, float* __restrict__ AS, float* __restrict__ AD) {

    constexpr int BM = 64, BN = 128, BK = 32;
    __shared__ float As[BK][68];    // 8.7 KB
    __shared__ float Bs[BK][132];   // 16.9 KB

    const int tid = threadIdx.x;
    const int tx  = tid & 31;        // 0..31 -> col group
    const int ty  = tid >> 5;        // 0..7  -> row group
    const int row0 = blockIdx.x * BM;
    const int col0 = blockIdx.y * BN;

    float acc[8][4];
#pragma unroll
    for (int i = 0; i < 8; ++i)
#pragma unroll
        for (int j = 0; j < 4; ++j) acc[i][j] = 0.f;

    for (int k0 = 0; k0 < K; k0 += BK) {
        // ---- stage A: 64 rows x 32 k, transposed into As[k][m] ----
#pragma unroll
        for (int j = 0; j < 2; ++j) {
            int idx = tid + 256 * j;          // 0..511
            int m   = idx >> 3;               // 0..63
            int kq  = (idx & 7) * 4;          // 0,4,..,28
            int gr  = row0 + m;
            float4 v = make_float4(0.f, 0.f, 0.f, 0.f);
            if (gr < NNODES)
                v = *reinterpret_cast<const float4*>(&X[(size_t)gr * K + k0 + kq]);
            As[kq + 0][m] = v.x;
            As[kq + 1][m] = v.y;
            As[kq + 2][m] = v.z;
            As[kq + 3][m] = v.w;
        }
        // ---- stage B: 32 k x 128 cols ----
#pragma unroll
        for (int j = 0; j < 4; ++j) {
            int idx = tid + 256 * j;          // 0..1023
            int kk  = idx >> 5;               // 0..31
            int cq  = (idx & 31) * 4;         // 0..124
            float4 v = *reinterpret_cast<const float4*>(&W[(size_t)(k0 + kk) * FH + col0 + cq]);
            *reinterpret_cast<float4*>(&Bs[kk][cq]) = v;
        }
        __syncthreads();

#pragma unroll 4
        for (int kk = 0; kk < BK; ++kk) {
            float4 a0 = *reinterpret_cast<const float4*>(&As[kk][ty * 8]);
            float4 a1 = *reinterpret_cast<const float4*>(&As[kk][ty * 8 + 4]);
            float4 b  = *reinterpret_cast<const float4*>(&Bs[kk][tx * 4]);
            float av[8] = {a0.x, a0.y, a0.z, a0.w, a1.x, a1.y, a1.z, a1.w};
#pragma unroll
            for (int i = 0; i < 8; ++i) {
                acc[i][0] = fmaf(av[i], b.x, acc[i][0]);
                acc[i][1] = fmaf(av[i], b.y, acc[i][1]);
                acc[i][2] = fmaf(av[i], b.z, acc[i][2]);
                acc[i][3] = fmaf(av[i], b.w, acc[i][3]);
            }
        }
        __syncthreads();
    }

    // ---- epilogue: store h + fused per-head alpha dot products ----
    const int col   = col0 + tx * 4;
    const int head  = tx >> 3;                // 0..3 within N-tile
    const int ghead = blockIdx.y * 4 + head;  // global head
    const float4 asw = *reinterpret_cast<const float4*>(&ASRC[col]);
    const float4 adw = *reinterpret_cast<const float4*>(&ADST[col]);

#pragma unroll
    for (int i = 0; i < 8; ++i) {
        int row = row0 + ty * 8 + i;
        if (row >= NNODES) break;     // uniform across the 8-lane reduce group
        float4 v = make_float4(acc[i][0], acc[i][1], acc[i][2], acc[i][3]);
        *reinterpret_cast<float4*>(&Hout[(size_t)row * FH + col]) = v;
        float ps = fmaf(v.x, asw.x, fmaf(v.y, asw.y, fmaf(v.z, asw.z, v.w * asw.w)));
        float pd = fmaf(v.x, adw.x, fmaf(v.y, adw.y, fmaf(v.z, adw.z, v.w * adw.w)));
#pragma unroll
        for (int off = 4; off >= 1; off >>= 1) {
            ps += __shfl_xor(ps, off);
            pd += __shfl_xor(pd, off);
        }
        if ((tx & 7) == 0) {
            AS[row * NH + ghead] = ps;
            AD[row * NH + ghead] = pd;
        }
    }
}

// ---------------- Per-node gather aggregation: one WAVE per node ----------------
// Lane owns 4 channels (float4). Every lane walks all edges of its node, so
// per-head denominators (identical within each 8-lane group) and per-channel
// accumulators complete with NO shuffles, NO LDS, NO barriers.
// No max-subtraction: scores ~ N(0,2); max over 4M samples ~ 7.8 -> exp safe
// in fp32, and the max factor cancels exactly in the normalization.
template<bool FINAL>
__global__ __launch_bounds__(256) void aggregate(
    const float* __restrict__ HF, const float* __restrict__ AS, const float* __restrict__ AD,
    const int* __restrict__ rp, const int* __restrict__ ssrc,
    const float* __restrict__ BIAS,
    float* __restrict__ XOUT,
    const float* __restrict__ WL, const float* __restrict__ BL,
    float* __restrict__ OUT) {

    const int tid  = threadIdx.x;
    const int lane = tid & 63;
    const int i    = __builtin_amdgcn_readfirstlane(blockIdx.x * 4 + (tid >> 6));
    const int hh   = lane >> 3;       // head of this lane's 4 channels
    const int c4   = lane * 4;        // first owned channel

    const float  ad   = AD[i * NH + hh];
    const float4 bias = *reinterpret_cast<const float4*>(&BIAS[c4]);

    const int p0  = rp[i];
    const int deg = rp[i + 1] - p0;

    float4 acc = make_float4(0.f, 0.f, 0.f, 0.f);
    float  den = 0.f;

#pragma unroll 2
    for (int e = 0; e < deg; ++e) {
        int s = ssrc[p0 + e];
        float sv = AS[s * NH + hh] + ad;
        sv = sv > 0.f ? sv : 0.2f * sv;
        float w = __expf(sv);
        den += w;
        const float4 hv = *reinterpret_cast<const float4*>(&HF[(size_t)s * FH + c4]);
        acc.x = fmaf(w, hv.x, acc.x);
        acc.y = fmaf(w, hv.y, acc.y);
        acc.z = fmaf(w, hv.z, acc.z);
        acc.w = fmaf(w, hv.w, acc.w);
    }

    const float inv = 1.f / (den + 1e-16f);
    float4 o;
    o.x = acc.x * inv + bias.x;
    o.y = acc.y * inv + bias.y;
    o.z = acc.z * inv + bias.z;
    o.w = acc.w * inv + bias.w;
    o.x = o.x > 0.f ? o.x : expm1f(o.x);
    o.y = o.y > 0.f ? o.y : expm1f(o.y);
    o.z = o.z > 0.f ? o.z : expm1f(o.z);
    o.w = o.w > 0.f ? o.w : expm1f(o.w);

    if (!FINAL) {
        *reinterpret_cast<float4*>(&XOUT[(size_t)i * FH + c4]) = o;
    } else {
        const float4 wl = *reinterpret_cast<const float4*>(&WL[c4]);
        float pl = fmaf(o.x, wl.x, fmaf(o.y, wl.y, fmaf(o.z, wl.z, o.w * wl.w)));
#pragma unroll
        for (int off = 32; off >= 1; off >>= 1) pl += __shfl_xor(pl, off);
        if (lane == 0) OUT[i] = pl + BL[0];
    }
}

// ---------------- launch ----------------
extern "C" void kernel_launch(void* const* d_in, const int* in_sizes, int n_in,
                              void* d_out, int out_size, void* d_ws, size_t ws_size,
                              hipStream_t stream) {
    const float* x   = (const float*)d_in[0];
    const int*   ei  = (const int*)d_in[1];
    const float* W1  = (const float*)d_in[2];
    const float* a1s = (const float*)d_in[3];
    const float* a1d = (const float*)d_in[4];
    const float* b1  = (const float*)d_in[5];
    const float* W2  = (const float*)d_in[6];
    const float* a2s = (const float*)d_in[7];
    const float* a2d = (const float*)d_in[8];
    const float* b2  = (const float*)d_in[9];
    const float* Wl  = (const float*)d_in[10];
    const float* bl  = (const float*)d_in[11];
    float* out = (float*)d_out;

    char* w = (char*)d_ws;
    auto alloc = [&](size_t bytes) -> char* {
        char* p = w;
        w += (bytes + 255) & ~size_t(255);
        return p;
    };
    int*   counts = (int*)alloc((size_t)NNODES * 4);
    int*   rp     = (int*)alloc((size_t)(NNODES + 1) * 4);
    int*   cursor = (int*)alloc((size_t)NNODES * 4);
    int*   ssrc   = (int*)alloc((size_t)TE * 4);
    float* hlin   = (float*)alloc((size_t)NNODES * FH * 4);
    float* x2     = (float*)alloc((size_t)NNODES * FH * 4);
    float* asb    = (float*)alloc((size_t)NNODES * NH * 4);
    float* adb    = (float*)alloc((size_t)NNODES * NH * 4);

    hipMemsetAsync(counts, 0, (size_t)NNODES * 4, stream);
    count_kernel<<<(TE + 255) / 256, 256, 0, stream>>>(ei, counts);
    scan_kernel<<<1, 1024, 0, stream>>>(counts, rp, cursor);
    fill_kernel<<<(TE + 255) / 256, 256, 0, stream>>>(ei, cursor, ssrc);

    const dim3 ggrid((NNODES + 63) / 64, FH / 128);
    gemm_tile<128><<<ggrid, 256, 0, stream>>>(x, W1, a1s, a1d, hlin, asb, adb);
    aggregate<false><<<NNODES / 4, 256, 0, stream>>>(hlin, asb, adb, rp, ssrc, b1, x2,
                                                     nullptr, nullptr, nullptr);
    gemm_tile<256><<<ggrid, 256, 0, stream>>>(x2, W2, a2s, a2d, hlin, asb, adb);
    aggregate<true><<<NNODES / 4, 256, 0, stream>>>(hlin, asb, adb, rp, ssrc, b2, nullptr,
                                                    Wl, bl, out);
}

// Round 4
// 302.834 us; speedup vs baseline: 1.6584x; 1.1697x over previous
//
#include <hip/hip_runtime.h>
#include <hip/hip_bf16.h>

#define NNODES 30000
#define NEDGES 480000
#define TE (NEDGES + NNODES)   // edges incl. self-loops
#define FH 256                 // hidden width (H*C)
#define NH 8                   // heads

// ---------------- CSR build (dst-sorted src lists) ----------------
__global__ void count_kernel(const int* __restrict__ ei, int* __restrict__ counts) {
    int e = blockIdx.x * 256 + threadIdx.x;
    if (e >= TE) return;
    int d = (e < NEDGES) ? ei[NEDGES + e] : (e - NEDGES);
    atomicAdd(&counts[d], 1);
}

__global__ __launch_bounds__(1024) void scan_kernel(const int* __restrict__ counts,
                                                    int* __restrict__ rp,
                                                    int* __restrict__ cursor) {
    __shared__ int part[1024];
    const int tid = threadIdx.x;
    const int chunk = (NNODES + 1023) / 1024;   // 30
    int lo = tid * chunk, hi = min(lo + chunk, NNODES);
    int s = 0;
    for (int i = lo; i < hi; ++i) s += counts[i];
    part[tid] = s;
    __syncthreads();
    // Hillis-Steele inclusive scan
    for (int off = 1; off < 1024; off <<= 1) {
        int v = (tid >= off) ? part[tid - off] : 0;
        __syncthreads();
        part[tid] += v;
        __syncthreads();
    }
    int run = part[tid] - s;   // exclusive prefix
    for (int i = lo; i < hi; ++i) {
        rp[i] = run; cursor[i] = run;
        run += counts[i];
    }
    if (tid == 1023) rp[NNODES] = part[1023];
}

__global__ void fill_kernel(const int* __restrict__ ei, int* __restrict__ cursor,
                            int* __restrict__ ssrc) {
    int e = blockIdx.x * 256 + threadIdx.x;
    if (e >= TE) return;
    int s, d;
    if (e < NEDGES) { s = ei[e]; d = ei[NEDGES + e]; }
    else            { s = e - NEDGES; d = s; }
    int pos = atomicAdd(&cursor[d], 1);
    ssrc[pos] = s;
}

// float -> bf16 (round to nearest even), values are finite
__device__ __forceinline__ unsigned short f2bf(float f) {
    unsigned u = __float_as_uint(f);
    u += 0x7fffu + ((u >> 16) & 1u);
    return (unsigned short)(u >> 16);
}
__device__ __forceinline__ float bfl(unsigned u) {            // low bf16 of dword
    return __uint_as_float(u << 16);
}
__device__ __forceinline__ float bfh(unsigned u) {            // high bf16 of dword
    return __uint_as_float(u & 0xffff0000u);
}

// ---------------- Register-tiled fp32 GEMM (h = X @ W) + fused alpha dots ----
// BM=64 x BN=128 tile, BK=32, 256 threads, 8x4 micro-tile per thread.
// Emits h as bf16 rows (the only consumer is the gather in aggregate).
template<int K>
__global__ __launch_bounds__(256) void gemm_tile(
    const float* __restrict__ X, const float* __restrict__ W,
    const float* __restrict__ ASRC, const float* __restrict__ ADST,
    unsigned short* __restrict__ HFb, float* __restrict__ AS, float* __restrict__ AD) {

    constexpr int BM = 64, BN = 128, BK = 32;
    __shared__ float As[BK][68];    // 8.7 KB
    __shared__ float Bs[BK][132];   // 16.9 KB

    const int tid = threadIdx.x;
    const int tx  = tid & 31;        // 0..31 -> col group
    const int ty  = tid >> 5;        // 0..7  -> row group
    const int row0 = blockIdx.x * BM;
    const int col0 = blockIdx.y * BN;

    float acc[8][4];
#pragma unroll
    for (int i = 0; i < 8; ++i)
#pragma unroll
        for (int j = 0; j < 4; ++j) acc[i][j] = 0.f;

    for (int k0 = 0; k0 < K; k0 += BK) {
        // ---- stage A: 64 rows x 32 k, transposed into As[k][m] ----
#pragma unroll
        for (int j = 0; j < 2; ++j) {
            int idx = tid + 256 * j;          // 0..511
            int m   = idx >> 3;               // 0..63
            int kq  = (idx & 7) * 4;          // 0,4,..,28
            int gr  = row0 + m;
            float4 v = make_float4(0.f, 0.f, 0.f, 0.f);
            if (gr < NNODES)
                v = *reinterpret_cast<const float4*>(&X[(size_t)gr * K + k0 + kq]);
            As[kq + 0][m] = v.x;
            As[kq + 1][m] = v.y;
            As[kq + 2][m] = v.z;
            As[kq + 3][m] = v.w;
        }
        // ---- stage B: 32 k x 128 cols ----
#pragma unroll
        for (int j = 0; j < 4; ++j) {
            int idx = tid + 256 * j;          // 0..1023
            int kk  = idx >> 5;               // 0..31
            int cq  = (idx & 31) * 4;         // 0..124
            float4 v = *reinterpret_cast<const float4*>(&W[(size_t)(k0 + kk) * FH + col0 + cq]);
            *reinterpret_cast<float4*>(&Bs[kk][cq]) = v;
        }
        __syncthreads();

#pragma unroll 4
        for (int kk = 0; kk < BK; ++kk) {
            float4 a0 = *reinterpret_cast<const float4*>(&As[kk][ty * 8]);
            float4 a1 = *reinterpret_cast<const float4*>(&As[kk][ty * 8 + 4]);
            float4 b  = *reinterpret_cast<const float4*>(&Bs[kk][tx * 4]);
            float av[8] = {a0.x, a0.y, a0.z, a0.w, a1.x, a1.y, a1.z, a1.w};
#pragma unroll
            for (int i = 0; i < 8; ++i) {
                acc[i][0] = fmaf(av[i], b.x, acc[i][0]);
                acc[i][1] = fmaf(av[i], b.y, acc[i][1]);
                acc[i][2] = fmaf(av[i], b.z, acc[i][2]);
                acc[i][3] = fmaf(av[i], b.w, acc[i][3]);
            }
        }
        __syncthreads();
    }

    // ---- epilogue: store h (bf16) + fused per-head alpha dot products ----
    const int col   = col0 + tx * 4;
    const int head  = tx >> 3;                // 0..3 within N-tile
    const int ghead = blockIdx.y * 4 + head;  // global head
    const float4 asw = *reinterpret_cast<const float4*>(&ASRC[col]);
    const float4 adw = *reinterpret_cast<const float4*>(&ADST[col]);

#pragma unroll
    for (int i = 0; i < 8; ++i) {
        int row = row0 + ty * 8 + i;
        if (row >= NNODES) break;     // uniform across the 8-lane reduce group
        float4 v = make_float4(acc[i][0], acc[i][1], acc[i][2], acc[i][3]);
        uint2 pk;
        pk.x = (unsigned)f2bf(v.x) | ((unsigned)f2bf(v.y) << 16);
        pk.y = (unsigned)f2bf(v.z) | ((unsigned)f2bf(v.w) << 16);
        *reinterpret_cast<uint2*>(&HFb[(size_t)row * FH + col]) = pk;
        float ps = fmaf(v.x, asw.x, fmaf(v.y, asw.y, fmaf(v.z, asw.z, v.w * asw.w)));
        float pd = fmaf(v.x, adw.x, fmaf(v.y, adw.y, fmaf(v.z, adw.z, v.w * adw.w)));
#pragma unroll
        for (int off = 4; off >= 1; off >>= 1) {
            ps += __shfl_xor(ps, off);
            pd += __shfl_xor(pd, off);
        }
        if ((tx & 7) == 0) {
            AS[row * NH + ghead] = ps;
            AD[row * NH + ghead] = pd;
        }
    }
}

// ---------------- Per-node gather aggregation: one WAVE per node ----------------
// bf16 h-rows (512B). Lane owns 8 channels (one 16B load); 32 lanes cover the
// row; the two wave halves process 2 edges in parallel, combined at the end
// with xor-32 shuffles. No LDS, no barriers, no max pass (exp args bounded).
template<bool FINAL>
__global__ __launch_bounds__(256) void aggregate(
    const unsigned short* __restrict__ HFb, const float* __restrict__ AS,
    const float* __restrict__ AD,
    const int* __restrict__ rp, const int* __restrict__ ssrc,
    const float* __restrict__ BIAS,
    float* __restrict__ XOUT,
    const float* __restrict__ WL, const float* __restrict__ BL,
    float* __restrict__ OUT) {

    const int tid  = threadIdx.x;
    const int lane = tid & 63;
    const int node = __builtin_amdgcn_readfirstlane(blockIdx.x * 4 + (tid >> 6));
    const int epar = lane >> 5;        // which edge of the pair
    const int cg   = lane & 31;        // channel group: owns channels cg*8..cg*8+7
    const int hh   = cg >> 2;          // head of these channels
    const int c8   = cg * 8;

    const float ad = AD[node * NH + hh];
    const int p0   = rp[node];
    const int deg  = rp[node + 1] - p0;   // >= 1 (self-loop)

    float a0=0.f,a1=0.f,a2=0.f,a3=0.f,a4=0.f,a5=0.f,a6=0.f,a7=0.f;
    float den = 0.f;

#pragma unroll 2
    for (int e0 = 0; e0 < deg; e0 += 2) {
        const int  e   = e0 + epar;
        const bool act = e < deg;
        const int  sa  = ssrc[p0 + (act ? e : 0)];
        const float asv = AS[sa * NH + hh];
        const uint4 hv  = *reinterpret_cast<const uint4*>(&HFb[(size_t)sa * FH + c8]);
        float sv = asv + ad;
        sv = sv > 0.f ? sv : 0.2f * sv;
        const float w = act ? __expf(sv) : 0.f;
        den += w;
        a0 = fmaf(w, bfl(hv.x), a0);
        a1 = fmaf(w, bfh(hv.x), a1);
        a2 = fmaf(w, bfl(hv.y), a2);
        a3 = fmaf(w, bfh(hv.y), a3);
        a4 = fmaf(w, bfl(hv.z), a4);
        a5 = fmaf(w, bfh(hv.z), a5);
        a6 = fmaf(w, bfl(hv.w), a6);
        a7 = fmaf(w, bfh(hv.w), a7);
    }

    // combine the two edge-parallel halves
    a0 += __shfl_xor(a0, 32); a1 += __shfl_xor(a1, 32);
    a2 += __shfl_xor(a2, 32); a3 += __shfl_xor(a3, 32);
    a4 += __shfl_xor(a4, 32); a5 += __shfl_xor(a5, 32);
    a6 += __shfl_xor(a6, 32); a7 += __shfl_xor(a7, 32);
    den += __shfl_xor(den, 32);

    const float inv = 1.f / (den + 1e-16f);
    const float4 b0 = *reinterpret_cast<const float4*>(&BIAS[c8]);
    const float4 b1 = *reinterpret_cast<const float4*>(&BIAS[c8 + 4]);
    float o[8];
    o[0] = fmaf(a0, inv, b0.x); o[1] = fmaf(a1, inv, b0.y);
    o[2] = fmaf(a2, inv, b0.z); o[3] = fmaf(a3, inv, b0.w);
    o[4] = fmaf(a4, inv, b1.x); o[5] = fmaf(a5, inv, b1.y);
    o[6] = fmaf(a6, inv, b1.z); o[7] = fmaf(a7, inv, b1.w);
#pragma unroll
    for (int j = 0; j < 8; ++j) o[j] = o[j] > 0.f ? o[j] : expm1f(o[j]);

    if (!FINAL) {
        // epar half 0 stores channels c8..c8+3, half 1 stores c8+4..c8+7
        float4 st = epar ? make_float4(o[4], o[5], o[6], o[7])
                         : make_float4(o[0], o[1], o[2], o[3]);
        *reinterpret_cast<float4*>(&XOUT[(size_t)node * FH + c8 + epar * 4]) = st;
    } else {
        const float4 w0 = *reinterpret_cast<const float4*>(&WL[c8]);
        const float4 w1 = *reinterpret_cast<const float4*>(&WL[c8 + 4]);
        float pl = fmaf(o[0], w0.x, fmaf(o[1], w0.y, fmaf(o[2], w0.z, o[3] * w0.w)));
        pl = fmaf(o[4], w1.x, fmaf(o[5], w1.y, fmaf(o[6], w1.z, fmaf(o[7], w1.w, pl))));
        // both halves hold identical pl; reduce across the 32 channel groups
#pragma unroll
        for (int off = 16; off >= 1; off >>= 1) pl += __shfl_xor(pl, off);
        if (lane == 0) OUT[node] = pl + BL[0];
    }
}

// ---------------- launch ----------------
extern "C" void kernel_launch(void* const* d_in, const int* in_sizes, int n_in,
                              void* d_out, int out_size, void* d_ws, size_t ws_size,
                              hipStream_t stream) {
    const float* x   = (const float*)d_in[0];
    const int*   ei  = (const int*)d_in[1];
    const float* W1  = (const float*)d_in[2];
    const float* a1s = (const float*)d_in[3];
    const float* a1d = (const float*)d_in[4];
    const float* b1  = (const float*)d_in[5];
    const float* W2  = (const float*)d_in[6];
    const float* a2s = (const float*)d_in[7];
    const float* a2d = (const float*)d_in[8];
    const float* b2  = (const float*)d_in[9];
    const float* Wl  = (const float*)d_in[10];
    const float* bl  = (const float*)d_in[11];
    float* out = (float*)d_out;

    char* w = (char*)d_ws;
    auto alloc = [&](size_t bytes) -> char* {
        char* p = w;
        w += (bytes + 255) & ~size_t(255);
        return p;
    };
    int*   counts = (int*)alloc((size_t)NNODES * 4);
    int*   rp     = (int*)alloc((size_t)(NNODES + 1) * 4);
    int*   cursor = (int*)alloc((size_t)NNODES * 4);
    int*   ssrc   = (int*)alloc((size_t)TE * 4);
    unsigned short* hfb = (unsigned short*)alloc((size_t)NNODES * FH * 2);
    float* x2     = (float*)alloc((size_t)NNODES * FH * 4);
    float* asb    = (float*)alloc((size_t)NNODES * NH * 4);
    float* adb    = (float*)alloc((size_t)NNODES * NH * 4);

    hipMemsetAsync(counts, 0, (size_t)NNODES * 4, stream);
    count_kernel<<<(TE + 255) / 256, 256, 0, stream>>>(ei, counts);
    scan_kernel<<<1, 1024, 0, stream>>>(counts, rp, cursor);
    fill_kernel<<<(TE + 255) / 256, 256, 0, stream>>>(ei, cursor, ssrc);

    const dim3 ggrid((NNODES + 63) / 64, FH / 128);
    gemm_tile<128><<<ggrid, 256, 0, stream>>>(x, W1, a1s, a1d, hfb, asb, adb);
    aggregate<false><<<NNODES / 4, 256, 0, stream>>>(hfb, asb, adb, rp, ssrc, b1, x2,
                                                     nullptr, nullptr, nullptr);
    gemm_tile<256><<<ggrid, 256, 0, stream>>>(x2, W2, a2s, a2d, hfb, asb, adb);
    aggregate<true><<<NNODES / 4, 256, 0, stream>>>(hfb, asb, adb, rp, ssrc, b2, nullptr,
                                                    Wl, bl, out);
}

// Round 5
// 266.517 us; speedup vs baseline: 1.8844x; 1.1363x over previous
//
#include <hip/hip_runtime.h>
#include <hip/hip_bf16.h>

#define NNODES 30000
#define NEDGES 480000
#define TE (NEDGES + NNODES)   // edges incl. self-loops
#define FH 256                 // hidden width (H*C)
#define NH 8                   // heads

typedef unsigned short ushort_t;
typedef __attribute__((ext_vector_type(8))) short bf16x8;
typedef __attribute__((ext_vector_type(4))) float f32x4;

// ---------------- CSR build (dst-sorted src lists) ----------------
__global__ void count_kernel(const int* __restrict__ ei, int* __restrict__ counts) {
    int e = blockIdx.x * 256 + threadIdx.x;
    if (e >= TE) return;
    int d = (e < NEDGES) ? ei[NEDGES + e] : (e - NEDGES);
    atomicAdd(&counts[d], 1);
}

__global__ __launch_bounds__(1024) void scan_kernel(const int* __restrict__ counts,
                                                    int* __restrict__ rp,
                                                    int* __restrict__ cursor) {
    __shared__ int part[1024];
    const int tid = threadIdx.x;
    const int chunk = (NNODES + 1023) / 1024;   // 30
    int lo = tid * chunk, hi = min(lo + chunk, NNODES);
    int s = 0;
    for (int i = lo; i < hi; ++i) s += counts[i];
    part[tid] = s;
    __syncthreads();
    for (int off = 1; off < 1024; off <<= 1) {
        int v = (tid >= off) ? part[tid - off] : 0;
        __syncthreads();
        part[tid] += v;
        __syncthreads();
    }
    int run = part[tid] - s;   // exclusive prefix
    for (int i = lo; i < hi; ++i) {
        rp[i] = run; cursor[i] = run;
        run += counts[i];
    }
    if (tid == 1023) rp[NNODES] = part[1023];
}

__global__ void fill_kernel(const int* __restrict__ ei, int* __restrict__ cursor,
                            int* __restrict__ ssrc) {
    int e = blockIdx.x * 256 + threadIdx.x;
    if (e >= TE) return;
    int s, d;
    if (e < NEDGES) { s = ei[e]; d = ei[NEDGES + e]; }
    else            { s = e - NEDGES; d = s; }
    int pos = atomicAdd(&cursor[d], 1);
    ssrc[pos] = s;
}

// ---------------- bf16 helpers ----------------
__device__ __forceinline__ ushort_t f2bf(float f) {           // RNE, finite inputs
    unsigned u = __float_as_uint(f);
    u += 0x7fffu + ((u >> 16) & 1u);
    return (ushort_t)(u >> 16);
}
__device__ __forceinline__ float bf2f(ushort_t h) {
    return __uint_as_float((unsigned)h << 16);
}
__device__ __forceinline__ float bfl(unsigned u) { return __uint_as_float(u << 16); }
__device__ __forceinline__ float bfh(unsigned u) { return __uint_as_float(u & 0xffff0000u); }

// ---------------- prepass: split fp32 -> bf16 hi/lo ----------------
__global__ void split_x_kernel(const float* __restrict__ X,
                               ushort_t* __restrict__ hi, ushort_t* __restrict__ lo,
                               int nquads) {
    int i = blockIdx.x * 256 + threadIdx.x;
    if (i >= nquads) return;
    float4 v = *reinterpret_cast<const float4*>(&X[(size_t)i * 4]);
    ushort_t h0 = f2bf(v.x), h1 = f2bf(v.y), h2 = f2bf(v.z), h3 = f2bf(v.w);
    ushort_t l0 = f2bf(v.x - bf2f(h0)), l1 = f2bf(v.y - bf2f(h1));
    ushort_t l2 = f2bf(v.z - bf2f(h2)), l3 = f2bf(v.w - bf2f(h3));
    uint2 hp, lp;
    hp.x = (unsigned)h0 | ((unsigned)h1 << 16); hp.y = (unsigned)h2 | ((unsigned)h3 << 16);
    lp.x = (unsigned)l0 | ((unsigned)l1 << 16); lp.y = (unsigned)l2 | ((unsigned)l3 << 16);
    *reinterpret_cast<uint2*>(&hi[(size_t)i * 4]) = hp;
    *reinterpret_cast<uint2*>(&lo[(size_t)i * 4]) = lp;
}

// W [K][256] row-major -> Wt_hi/lo [256][K] (n-major) split
template<int K>
__global__ void splitT_w(const float* __restrict__ W,
                         ushort_t* __restrict__ th, ushort_t* __restrict__ tl) {
    int idx = blockIdx.x * 256 + threadIdx.x;   // n fast -> coalesced read
    if (idx >= 256 * K) return;
    int n = idx & 255, k = idx >> 8;
    float v = W[idx];
    ushort_t h = f2bf(v);
    ushort_t l = f2bf(v - bf2f(h));
    th[n * K + k] = h;
    tl[n * K + k] = l;
}

// ---------------- bf16x3 MFMA GEMM (h = X @ W) + fused alpha dots ----------------
// BM=128 x BN=128, BK=32, 256 threads = 4 waves of 64x64 (4x4 frags 16x16x32).
// A = Ahi+Alo, B = Bhi+Blo (bf16 splits); acc += Ahi*Bhi + Ahi*Blo + Alo*Bhi.
template<int K>
__global__ __launch_bounds__(256) void gemm_mfma(
    const ushort_t* __restrict__ Ahi, const ushort_t* __restrict__ Alo,   // [M][K]
    const ushort_t* __restrict__ Bth, const ushort_t* __restrict__ Btl,   // [256][K]
    const float* __restrict__ ASRC, const float* __restrict__ ADST,
    ushort_t* __restrict__ HFb, float* __restrict__ AS, float* __restrict__ AD) {

    constexpr int LDK = 40;   // pad: 80B row stride = 20 banks, 16B aligned
    __shared__ ushort_t Ah[128][LDK], Al[128][LDK], Bh[128][LDK], Bl[128][LDK];

    const int tid  = threadIdx.x;
    const int lane = tid & 63;
    const int wid  = tid >> 6;
    const int m0 = blockIdx.x * 128;
    const int n0 = blockIdx.y * 128;
    const int wm = (wid & 1) * 64, wn = (wid >> 1) * 64;
    const int q = lane >> 4;          // quarter-wave
    const int c = lane & 15;

    f32x4 acc[4][4];
#pragma unroll
    for (int mi = 0; mi < 4; ++mi)
#pragma unroll
        for (int ni = 0; ni < 4; ++ni) acc[mi][ni] = (f32x4){0.f, 0.f, 0.f, 0.f};

    for (int k0 = 0; k0 < K; k0 += 32) {
        __syncthreads();
#pragma unroll
        for (int rep = 0; rep < 4; ++rep) {
            int idx = tid + 256 * rep;          // 0..1023
            int arr = idx >> 9;                 // 0: hi, 1: lo
            int rem = idx & 511;
            int row = rem >> 2;                 // 0..127
            int ch  = (rem & 3) * 8;            // k-chunk of 8 bf16
            // A tile
            int gr = m0 + row;
            uint4 v = make_uint4(0u, 0u, 0u, 0u);
            const ushort_t* asrc_g = arr ? Alo : Ahi;
            if (gr < NNODES)
                v = *reinterpret_cast<const uint4*>(&asrc_g[(size_t)gr * K + k0 + ch]);
            *reinterpret_cast<uint4*>(&(arr ? Al : Ah)[row][ch]) = v;
            // B tile (n-major global, no transpose needed)
            const ushort_t* bsrc_g = arr ? Btl : Bth;
            uint4 bv = *reinterpret_cast<const uint4*>(&bsrc_g[(size_t)(n0 + row) * K + k0 + ch]);
            *reinterpret_cast<uint4*>(&(arr ? Bl : Bh)[row][ch]) = bv;
        }
        __syncthreads();

        const int koff = q * 8;
        bf16x8 fah[4], fal[4], fbh[4], fbl[4];
#pragma unroll
        for (int mi = 0; mi < 4; ++mi) {
            int r = wm + mi * 16 + c;
            fah[mi] = *reinterpret_cast<const bf16x8*>(&Ah[r][koff]);
            fal[mi] = *reinterpret_cast<const bf16x8*>(&Al[r][koff]);
        }
#pragma unroll
        for (int ni = 0; ni < 4; ++ni) {
            int r = wn + ni * 16 + c;
            fbh[ni] = *reinterpret_cast<const bf16x8*>(&Bh[r][koff]);
            fbl[ni] = *reinterpret_cast<const bf16x8*>(&Bl[r][koff]);
        }
#pragma unroll
        for (int mi = 0; mi < 4; ++mi)
#pragma unroll
            for (int ni = 0; ni < 4; ++ni) {
                acc[mi][ni] = __builtin_amdgcn_mfma_f32_16x16x32_bf16(fah[mi], fbh[ni], acc[mi][ni], 0, 0, 0);
                acc[mi][ni] = __builtin_amdgcn_mfma_f32_16x16x32_bf16(fah[mi], fbl[ni], acc[mi][ni], 0, 0, 0);
                acc[mi][ni] = __builtin_amdgcn_mfma_f32_16x16x32_bf16(fal[mi], fbh[ni], acc[mi][ni], 0, 0, 0);
            }
    }

    // ---- epilogue: h (bf16) stores + fused per-head alpha dots (fp32 acc) ----
    float as_v[4], ad_v[4];
#pragma unroll
    for (int ni = 0; ni < 4; ++ni) {
        as_v[ni] = ASRC[n0 + wn + ni * 16 + c];
        ad_v[ni] = ADST[n0 + wn + ni * 16 + c];
    }
    const int head0 = (n0 + wn) >> 5;   // this wave covers heads head0, head0+1

#pragma unroll
    for (int mi = 0; mi < 4; ++mi) {
#pragma unroll
        for (int j = 0; j < 4; ++j) {
            int row = m0 + wm + mi * 16 + q * 4 + j;
            bool ok = row < NNODES;
            if (ok) {
#pragma unroll
                for (int ni = 0; ni < 4; ++ni)
                    HFb[(size_t)row * FH + n0 + wn + ni * 16 + c] = f2bf(acc[mi][ni][j]);
            }
            float ps0 = acc[mi][0][j] * as_v[0] + acc[mi][1][j] * as_v[1];
            float ps1 = acc[mi][2][j] * as_v[2] + acc[mi][3][j] * as_v[3];
            float pd0 = acc[mi][0][j] * ad_v[0] + acc[mi][1][j] * ad_v[1];
            float pd1 = acc[mi][2][j] * ad_v[2] + acc[mi][3][j] * ad_v[3];
#pragma unroll
            for (int off = 8; off >= 1; off >>= 1) {
                ps0 += __shfl_xor(ps0, off);
                ps1 += __shfl_xor(ps1, off);
                pd0 += __shfl_xor(pd0, off);
                pd1 += __shfl_xor(pd1, off);
            }
            if (ok && c == 0) {
                AS[row * NH + head0]     = ps0;
                AS[row * NH + head0 + 1] = ps1;
                AD[row * NH + head0]     = pd0;
                AD[row * NH + head0 + 1] = pd1;
            }
        }
    }
}

// ---------------- Per-node gather aggregation: one WAVE per node ----------------
template<bool FINAL>
__global__ __launch_bounds__(256) void aggregate(
    const ushort_t* __restrict__ HFb, const float* __restrict__ AS,
    const float* __restrict__ AD,
    const int* __restrict__ rp, const int* __restrict__ ssrc,
    const float* __restrict__ BIAS,
    ushort_t* __restrict__ XHI, ushort_t* __restrict__ XLO,
    const float* __restrict__ WL, const float* __restrict__ BL,
    float* __restrict__ OUT) {

    const int tid  = threadIdx.x;
    const int lane = tid & 63;
    const int node = __builtin_amdgcn_readfirstlane(blockIdx.x * 4 + (tid >> 6));
    const int epar = lane >> 5;        // which edge of the pair
    const int cg   = lane & 31;        // channel group: owns channels cg*8..cg*8+7
    const int hh   = cg >> 2;          // head of these channels
    const int c8   = cg * 8;

    const float ad = AD[node * NH + hh];
    const int p0   = rp[node];
    const int deg  = rp[node + 1] - p0;   // >= 1 (self-loop)

    float a0=0.f,a1=0.f,a2=0.f,a3=0.f,a4=0.f,a5=0.f,a6=0.f,a7=0.f;
    float den = 0.f;

#pragma unroll 2
    for (int e0 = 0; e0 < deg; e0 += 2) {
        const int  e   = e0 + epar;
        const bool act = e < deg;
        const int  sa  = ssrc[p0 + (act ? e : 0)];
        const float asv = AS[sa * NH + hh];
        const uint4 hv  = *reinterpret_cast<const uint4*>(&HFb[(size_t)sa * FH + c8]);
        float sv = asv + ad;
        sv = sv > 0.f ? sv : 0.2f * sv;
        const float w = act ? __expf(sv) : 0.f;
        den += w;
        a0 = fmaf(w, bfl(hv.x), a0);
        a1 = fmaf(w, bfh(hv.x), a1);
        a2 = fmaf(w, bfl(hv.y), a2);
        a3 = fmaf(w, bfh(hv.y), a3);
        a4 = fmaf(w, bfl(hv.z), a4);
        a5 = fmaf(w, bfh(hv.z), a5);
        a6 = fmaf(w, bfl(hv.w), a6);
        a7 = fmaf(w, bfh(hv.w), a7);
    }

    a0 += __shfl_xor(a0, 32); a1 += __shfl_xor(a1, 32);
    a2 += __shfl_xor(a2, 32); a3 += __shfl_xor(a3, 32);
    a4 += __shfl_xor(a4, 32); a5 += __shfl_xor(a5, 32);
    a6 += __shfl_xor(a6, 32); a7 += __shfl_xor(a7, 32);
    den += __shfl_xor(den, 32);

    const float inv = 1.f / (den + 1e-16f);
    const float4 b0 = *reinterpret_cast<const float4*>(&BIAS[c8]);
    const float4 b1 = *reinterpret_cast<const float4*>(&BIAS[c8 + 4]);
    float o[8];
    o[0] = fmaf(a0, inv, b0.x); o[1] = fmaf(a1, inv, b0.y);
    o[2] = fmaf(a2, inv, b0.z); o[3] = fmaf(a3, inv, b0.w);
    o[4] = fmaf(a4, inv, b1.x); o[5] = fmaf(a5, inv, b1.y);
    o[6] = fmaf(a6, inv, b1.z); o[7] = fmaf(a7, inv, b1.w);
#pragma unroll
    for (int j = 0; j < 8; ++j) o[j] = o[j] > 0.f ? o[j] : expm1f(o[j]);

    if (!FINAL) {
        // emit hi/lo bf16 split for the next GEMM (4 channels per half-wave)
        ushort_t hs[4], ls[4];
#pragma unroll
        for (int j = 0; j < 4; ++j) {
            float v = o[epar * 4 + j];
            hs[j] = f2bf(v);
            ls[j] = f2bf(v - bf2f(hs[j]));
        }
        uint2 hp, lp;
        hp.x = (unsigned)hs[0] | ((unsigned)hs[1] << 16);
        hp.y = (unsigned)hs[2] | ((unsigned)hs[3] << 16);
        lp.x = (unsigned)ls[0] | ((unsigned)ls[1] << 16);
        lp.y = (unsigned)ls[2] | ((unsigned)ls[3] << 16);
        *reinterpret_cast<uint2*>(&XHI[(size_t)node * FH + c8 + epar * 4]) = hp;
        *reinterpret_cast<uint2*>(&XLO[(size_t)node * FH + c8 + epar * 4]) = lp;
    } else {
        const float4 w0 = *reinterpret_cast<const float4*>(&WL[c8]);
        const float4 w1 = *reinterpret_cast<const float4*>(&WL[c8 + 4]);
        float pl = fmaf(o[0], w0.x, fmaf(o[1], w0.y, fmaf(o[2], w0.z, o[3] * w0.w)));
        pl = fmaf(o[4], w1.x, fmaf(o[5], w1.y, fmaf(o[6], w1.z, fmaf(o[7], w1.w, pl))));
#pragma unroll
        for (int off = 16; off >= 1; off >>= 1) pl += __shfl_xor(pl, off);
        if (lane == 0) OUT[node] = pl + BL[0];
    }
}

// ---------------- launch ----------------
extern "C" void kernel_launch(void* const* d_in, const int* in_sizes, int n_in,
                              void* d_out, int out_size, void* d_ws, size_t ws_size,
                              hipStream_t stream) {
    const float* x   = (const float*)d_in[0];
    const int*   ei  = (const int*)d_in[1];
    const float* W1  = (const float*)d_in[2];
    const float* a1s = (const float*)d_in[3];
    const float* a1d = (const float*)d_in[4];
    const float* b1  = (const float*)d_in[5];
    const float* W2  = (const float*)d_in[6];
    const float* a2s = (const float*)d_in[7];
    const float* a2d = (const float*)d_in[8];
    const float* b2  = (const float*)d_in[9];
    const float* Wl  = (const float*)d_in[10];
    const float* bl  = (const float*)d_in[11];
    float* out = (float*)d_out;

    char* w = (char*)d_ws;
    auto alloc = [&](size_t bytes) -> char* {
        char* p = w;
        w += (bytes + 255) & ~size_t(255);
        return p;
    };
    int*   counts = (int*)alloc((size_t)NNODES * 4);
    int*   rp     = (int*)alloc((size_t)(NNODES + 1) * 4);
    int*   cursor = (int*)alloc((size_t)NNODES * 4);
    int*   ssrc   = (int*)alloc((size_t)TE * 4);
    ushort_t* hfb = (ushort_t*)alloc((size_t)NNODES * FH * 2);
    // region A: xhi1 (layer1, [N][128]) then x2hi (layer2, [N][256]); region B: lo
    ushort_t* regA = (ushort_t*)alloc((size_t)NNODES * FH * 2);
    ushort_t* regB = (ushort_t*)alloc((size_t)NNODES * FH * 2);
    float* asb    = (float*)alloc((size_t)NNODES * NH * 4);
    float* adb    = (float*)alloc((size_t)NNODES * NH * 4);
    ushort_t* w1th = (ushort_t*)alloc((size_t)128 * 256 * 2);
    ushort_t* w1tl = (ushort_t*)alloc((size_t)128 * 256 * 2);
    ushort_t* w2th = (ushort_t*)alloc((size_t)256 * 256 * 2);
    ushort_t* w2tl = (ushort_t*)alloc((size_t)256 * 256 * 2);

    ushort_t* xhi1 = regA;   // [NNODES][128]
    ushort_t* xlo1 = regB;
    ushort_t* x2hi = regA;   // [NNODES][256] (reuse after gemm1 consumed xhi1)
    ushort_t* x2lo = regB;

    hipMemsetAsync(counts, 0, (size_t)NNODES * 4, stream);
    count_kernel<<<(TE + 255) / 256, 256, 0, stream>>>(ei, counts);
    scan_kernel<<<1, 1024, 0, stream>>>(counts, rp, cursor);
    fill_kernel<<<(TE + 255) / 256, 256, 0, stream>>>(ei, cursor, ssrc);

    const int xq = NNODES * 128 / 4;
    split_x_kernel<<<(xq + 255) / 256, 256, 0, stream>>>(x, xhi1, xlo1, xq);
    splitT_w<128><<<128, 256, 0, stream>>>(W1, w1th, w1tl);
    splitT_w<256><<<256, 256, 0, stream>>>(W2, w2th, w2tl);

    const dim3 ggrid((NNODES + 127) / 128, 2);
    gemm_mfma<128><<<ggrid, 256, 0, stream>>>(xhi1, xlo1, w1th, w1tl, a1s, a1d,
                                              hfb, asb, adb);
    aggregate<false><<<NNODES / 4, 256, 0, stream>>>(hfb, asb, adb, rp, ssrc, b1,
                                                     x2hi, x2lo, nullptr, nullptr, nullptr);
    gemm_mfma<256><<<ggrid, 256, 0, stream>>>(x2hi, x2lo, w2th, w2tl, a2s, a2d,
                                              hfb, asb, adb);
    aggregate<true><<<NNODES / 4, 256, 0, stream>>>(hfb, asb, adb, rp, ssrc, b2,
                                                    nullptr, nullptr, Wl, bl, out);
}

// Round 6
// 215.389 us; speedup vs baseline: 2.3317x; 1.2374x over previous
//
#include <hip/hip_runtime.h>
#include <hip/hip_bf16.h>

#define NNODES 30000
#define NEDGES 480000
#define TE (NEDGES + NNODES)   // edges incl. self-loops
#define FH 256                 // hidden width (H*C)
#define NH 8                   // heads
#define NSB ((NNODES + 255) / 256)   // scan blocks = 118

typedef unsigned short ushort_t;
typedef __attribute__((ext_vector_type(8))) short bf16x8;
typedef __attribute__((ext_vector_type(4))) float f32x4;

// ---------------- CSR build (dst-sorted src lists) ----------------
__global__ void count_kernel(const int* __restrict__ ei, int* __restrict__ counts) {
    int e = blockIdx.x * 256 + threadIdx.x;
    if (e >= TE) return;
    int d = (e < NEDGES) ? ei[NEDGES + e] : (e - NEDGES);
    atomicAdd(&counts[d], 1);
}

// hierarchical scan: (1) per-block local exclusive scan + block sums
__global__ __launch_bounds__(256) void scan1_kernel(const int* __restrict__ counts,
                                                    int* __restrict__ rp,
                                                    int* __restrict__ bsum) {
    __shared__ int s[256];
    const int tid = threadIdx.x;
    const int i = blockIdx.x * 256 + tid;
    int v = (i < NNODES) ? counts[i] : 0;
    s[tid] = v;
    __syncthreads();
    for (int off = 1; off < 256; off <<= 1) {
        int t = (tid >= off) ? s[tid - off] : 0;
        __syncthreads();
        s[tid] += t;
        __syncthreads();
    }
    if (i < NNODES) rp[i] = s[tid] - v;          // local exclusive prefix
    if (tid == 255) bsum[blockIdx.x] = s[255];
}

// (2) scan the 118 block sums in place (exclusive)
__global__ __launch_bounds__(128) void scan2_kernel(int* __restrict__ bsum) {
    __shared__ int s[128];
    const int tid = threadIdx.x;
    int v = (tid < NSB) ? bsum[tid] : 0;
    s[tid] = v;
    __syncthreads();
    for (int off = 1; off < 128; off <<= 1) {
        int t = (tid >= off) ? s[tid - off] : 0;
        __syncthreads();
        s[tid] += t;
        __syncthreads();
    }
    if (tid < NSB) bsum[tid] = s[tid] - v;
}

// (3) add block offsets, fan out to rp/cursor
__global__ __launch_bounds__(256) void scan3_kernel(int* __restrict__ rp,
                                                    const int* __restrict__ bsum,
                                                    int* __restrict__ cursor) {
    const int i = blockIdx.x * 256 + threadIdx.x;
    if (i < NNODES) {
        int r = rp[i] + bsum[blockIdx.x];
        rp[i] = r;
        cursor[i] = r;
    }
    if (i == 0) rp[NNODES] = TE;   // total is a compile-time constant
}

__global__ void fill_kernel(const int* __restrict__ ei, int* __restrict__ cursor,
                            int* __restrict__ ssrc) {
    int e = blockIdx.x * 256 + threadIdx.x;
    if (e >= TE) return;
    int s, d;
    if (e < NEDGES) { s = ei[e]; d = ei[NEDGES + e]; }
    else            { s = e - NEDGES; d = s; }
    int pos = atomicAdd(&cursor[d], 1);
    ssrc[pos] = s;
}

// ---------------- bf16 helpers ----------------
__device__ __forceinline__ ushort_t f2bf(float f) {           // RNE, finite inputs
    unsigned u = __float_as_uint(f);
    u += 0x7fffu + ((u >> 16) & 1u);
    return (ushort_t)(u >> 16);
}
__device__ __forceinline__ float bf2f(ushort_t h) {
    return __uint_as_float((unsigned)h << 16);
}
__device__ __forceinline__ float bfl(unsigned u) { return __uint_as_float(u << 16); }
__device__ __forceinline__ float bfh(unsigned u) { return __uint_as_float(u & 0xffff0000u); }

// ---------------- prepass: split fp32 -> bf16 hi/lo ----------------
__global__ void split_x_kernel(const float* __restrict__ X,
                               ushort_t* __restrict__ hi, ushort_t* __restrict__ lo,
                               int nquads) {
    int i = blockIdx.x * 256 + threadIdx.x;
    if (i >= nquads) return;
    float4 v = *reinterpret_cast<const float4*>(&X[(size_t)i * 4]);
    ushort_t h0 = f2bf(v.x), h1 = f2bf(v.y), h2 = f2bf(v.z), h3 = f2bf(v.w);
    ushort_t l0 = f2bf(v.x - bf2f(h0)), l1 = f2bf(v.y - bf2f(h1));
    ushort_t l2 = f2bf(v.z - bf2f(h2)), l3 = f2bf(v.w - bf2f(h3));
    uint2 hp, lp;
    hp.x = (unsigned)h0 | ((unsigned)h1 << 16); hp.y = (unsigned)h2 | ((unsigned)h3 << 16);
    lp.x = (unsigned)l0 | ((unsigned)l1 << 16); lp.y = (unsigned)l2 | ((unsigned)l3 << 16);
    *reinterpret_cast<uint2*>(&hi[(size_t)i * 4]) = hp;
    *reinterpret_cast<uint2*>(&lo[(size_t)i * 4]) = lp;
}

// W [K][256] row-major -> Wt_hi/lo [256][K] (n-major) split
template<int K>
__global__ void splitT_w(const float* __restrict__ W,
                         ushort_t* __restrict__ th, ushort_t* __restrict__ tl) {
    int idx = blockIdx.x * 256 + threadIdx.x;   // n fast -> coalesced read
    if (idx >= 256 * K) return;
    int n = idx & 255, k = idx >> 8;
    float v = W[idx];
    ushort_t h = f2bf(v);
    ushort_t l = f2bf(v - bf2f(h));
    th[n * K + k] = h;
    tl[n * K + k] = l;
}

// ---------------- bf16x3 MFMA GEMM (h = X @ W) + fused alpha dots ----------------
// BM=128 x BN=128, BK=32, 256 threads = 4 waves of 64x64 (4x4 frags 16x16x32).
// A = Ahi+Alo, B = Bhi+Blo (bf16 splits); acc += Ahi*Bhi + Ahi*Blo + Alo*Bhi.
template<int K>
__global__ __launch_bounds__(256) void gemm_mfma(
    const ushort_t* __restrict__ Ahi, const ushort_t* __restrict__ Alo,   // [M][K]
    const ushort_t* __restrict__ Bth, const ushort_t* __restrict__ Btl,   // [256][K]
    const float* __restrict__ ASRC, const float* __restrict__ ADST,
    ushort_t* __restrict__ HFb, float* __restrict__ AS, float* __restrict__ AD) {

    constexpr int LDK = 40;   // pad: 80B row stride = 20 banks, 16B aligned
    __shared__ ushort_t Ah[128][LDK], Al[128][LDK], Bh[128][LDK], Bl[128][LDK];

    const int tid  = threadIdx.x;
    const int lane = tid & 63;
    const int wid  = tid >> 6;
    const int m0 = blockIdx.x * 128;
    const int n0 = blockIdx.y * 128;
    const int wm = (wid & 1) * 64, wn = (wid >> 1) * 64;
    const int q = lane >> 4;          // quarter-wave
    const int c = lane & 15;

    f32x4 acc[4][4];
#pragma unroll
    for (int mi = 0; mi < 4; ++mi)
#pragma unroll
        for (int ni = 0; ni < 4; ++ni) acc[mi][ni] = (f32x4){0.f, 0.f, 0.f, 0.f};

    for (int k0 = 0; k0 < K; k0 += 32) {
        __syncthreads();
#pragma unroll
        for (int rep = 0; rep < 4; ++rep) {
            int idx = tid + 256 * rep;          // 0..1023
            int arr = idx >> 9;                 // 0: hi, 1: lo
            int rem = idx & 511;
            int row = rem >> 2;                 // 0..127
            int ch  = (rem & 3) * 8;            // k-chunk of 8 bf16
            // A tile
            int gr = m0 + row;
            uint4 v = make_uint4(0u, 0u, 0u, 0u);
            const ushort_t* asrc_g = arr ? Alo : Ahi;
            if (gr < NNODES)
                v = *reinterpret_cast<const uint4*>(&asrc_g[(size_t)gr * K + k0 + ch]);
            *reinterpret_cast<uint4*>(&(arr ? Al : Ah)[row][ch]) = v;
            // B tile (n-major global, no transpose needed)
            const ushort_t* bsrc_g = arr ? Btl : Bth;
            uint4 bv = *reinterpret_cast<const uint4*>(&bsrc_g[(size_t)(n0 + row) * K + k0 + ch]);
            *reinterpret_cast<uint4*>(&(arr ? Bl : Bh)[row][ch]) = bv;
        }
        __syncthreads();

        const int koff = q * 8;
        bf16x8 fah[4], fal[4], fbh[4], fbl[4];
#pragma unroll
        for (int mi = 0; mi < 4; ++mi) {
            int r = wm + mi * 16 + c;
            fah[mi] = *reinterpret_cast<const bf16x8*>(&Ah[r][koff]);
            fal[mi] = *reinterpret_cast<const bf16x8*>(&Al[r][koff]);
        }
#pragma unroll
        for (int ni = 0; ni < 4; ++ni) {
            int r = wn + ni * 16 + c;
            fbh[ni] = *reinterpret_cast<const bf16x8*>(&Bh[r][koff]);
            fbl[ni] = *reinterpret_cast<const bf16x8*>(&Bl[r][koff]);
        }
#pragma unroll
        for (int mi = 0; mi < 4; ++mi)
#pragma unroll
            for (int ni = 0; ni < 4; ++ni) {
                acc[mi][ni] = __builtin_amdgcn_mfma_f32_16x16x32_bf16(fah[mi], fbh[ni], acc[mi][ni], 0, 0, 0);
                acc[mi][ni] = __builtin_amdgcn_mfma_f32_16x16x32_bf16(fah[mi], fbl[ni], acc[mi][ni], 0, 0, 0);
                acc[mi][ni] = __builtin_amdgcn_mfma_f32_16x16x32_bf16(fal[mi], fbh[ni], acc[mi][ni], 0, 0, 0);
            }
    }

    // ---- epilogue: h (bf16) stores + fused per-head alpha dots (fp32 acc) ----
    float as_v[4], ad_v[4];
#pragma unroll
    for (int ni = 0; ni < 4; ++ni) {
        as_v[ni] = ASRC[n0 + wn + ni * 16 + c];
        ad_v[ni] = ADST[n0 + wn + ni * 16 + c];
    }
    const int head0 = (n0 + wn) >> 5;   // this wave covers heads head0, head0+1

#pragma unroll
    for (int mi = 0; mi < 4; ++mi) {
#pragma unroll
        for (int j = 0; j < 4; ++j) {
            int row = m0 + wm + mi * 16 + q * 4 + j;
            bool ok = row < NNODES;
            if (ok) {
#pragma unroll
                for (int ni = 0; ni < 4; ++ni)
                    HFb[(size_t)row * FH + n0 + wn + ni * 16 + c] = f2bf(acc[mi][ni][j]);
            }
            float ps0 = acc[mi][0][j] * as_v[0] + acc[mi][1][j] * as_v[1];
            float ps1 = acc[mi][2][j] * as_v[2] + acc[mi][3][j] * as_v[3];
            float pd0 = acc[mi][0][j] * ad_v[0] + acc[mi][1][j] * ad_v[1];
            float pd1 = acc[mi][2][j] * ad_v[2] + acc[mi][3][j] * ad_v[3];
#pragma unroll
            for (int off = 8; off >= 1; off >>= 1) {
                ps0 += __shfl_xor(ps0, off);
                ps1 += __shfl_xor(ps1, off);
                pd0 += __shfl_xor(pd0, off);
                pd1 += __shfl_xor(pd1, off);
            }
            if (ok && c == 0) {
                AS[row * NH + head0]     = ps0;
                AS[row * NH + head0 + 1] = ps1;
                AD[row * NH + head0]     = pd0;
                AD[row * NH + head0 + 1] = pd1;
            }
        }
    }
}

// ---------------- Per-node gather aggregation: one WAVE per node ----------------
template<bool FINAL>
__global__ __launch_bounds__(256) void aggregate(
    const ushort_t* __restrict__ HFb, const float* __restrict__ AS,
    const float* __restrict__ AD,
    const int* __restrict__ rp, const int* __restrict__ ssrc,
    const float* __restrict__ BIAS,
    ushort_t* __restrict__ XHI, ushort_t* __restrict__ XLO,
    const float* __restrict__ WL, const float* __restrict__ BL,
    float* __restrict__ OUT) {

    const int tid  = threadIdx.x;
    const int lane = tid & 63;
    const int node = __builtin_amdgcn_readfirstlane(blockIdx.x * 4 + (tid >> 6));
    const int epar = lane >> 5;        // which edge of the pair
    const int cg   = lane & 31;        // channel group: owns channels cg*8..cg*8+7
    const int hh   = cg >> 2;          // head of these channels
    const int c8   = cg * 8;

    const float ad = AD[node * NH + hh];
    const int p0   = rp[node];
    const int deg  = rp[node + 1] - p0;   // >= 1 (self-loop)

    float a0=0.f,a1=0.f,a2=0.f,a3=0.f,a4=0.f,a5=0.f,a6=0.f,a7=0.f;
    float den = 0.f;

#pragma unroll 2
    for (int e0 = 0; e0 < deg; e0 += 2) {
        const int  e   = e0 + epar;
        const bool act = e < deg;
        const int  sa  = ssrc[p0 + (act ? e : 0)];
        const float asv = AS[sa * NH + hh];
        const uint4 hv  = *reinterpret_cast<const uint4*>(&HFb[(size_t)sa * FH + c8]);
        float sv = asv + ad;
        sv = sv > 0.f ? sv : 0.2f * sv;
        const float w = act ? __expf(sv) : 0.f;
        den += w;
        a0 = fmaf(w, bfl(hv.x), a0);
        a1 = fmaf(w, bfh(hv.x), a1);
        a2 = fmaf(w, bfl(hv.y), a2);
        a3 = fmaf(w, bfh(hv.y), a3);
        a4 = fmaf(w, bfl(hv.z), a4);
        a5 = fmaf(w, bfh(hv.z), a5);
        a6 = fmaf(w, bfl(hv.w), a6);
        a7 = fmaf(w, bfh(hv.w), a7);
    }

    a0 += __shfl_xor(a0, 32); a1 += __shfl_xor(a1, 32);
    a2 += __shfl_xor(a2, 32); a3 += __shfl_xor(a3, 32);
    a4 += __shfl_xor(a4, 32); a5 += __shfl_xor(a5, 32);
    a6 += __shfl_xor(a6, 32); a7 += __shfl_xor(a7, 32);
    den += __shfl_xor(den, 32);

    const float inv = 1.f / (den + 1e-16f);
    const float4 b0 = *reinterpret_cast<const float4*>(&BIAS[c8]);
    const float4 b1 = *reinterpret_cast<const float4*>(&BIAS[c8 + 4]);
    float o[8];
    o[0] = fmaf(a0, inv, b0.x); o[1] = fmaf(a1, inv, b0.y);
    o[2] = fmaf(a2, inv, b0.z); o[3] = fmaf(a3, inv, b0.w);
    o[4] = fmaf(a4, inv, b1.x); o[5] = fmaf(a5, inv, b1.y);
    o[6] = fmaf(a6, inv, b1.z); o[7] = fmaf(a7, inv, b1.w);
#pragma unroll
    for (int j = 0; j < 8; ++j) o[j] = o[j] > 0.f ? o[j] : expm1f(o[j]);

    if (!FINAL) {
        // emit hi/lo bf16 split for the next GEMM (4 channels per half-wave)
        ushort_t hs[4], ls[4];
#pragma unroll
        for (int j = 0; j < 4; ++j) {
            float v = o[epar * 4 + j];
            hs[j] = f2bf(v);
            ls[j] = f2bf(v - bf2f(hs[j]));
        }
        uint2 hp, lp;
        hp.x = (unsigned)hs[0] | ((unsigned)hs[1] << 16);
        hp.y = (unsigned)hs[2] | ((unsigned)hs[3] << 16);
        lp.x = (unsigned)ls[0] | ((unsigned)ls[1] << 16);
        lp.y = (unsigned)ls[2] | ((unsigned)ls[3] << 16);
        *reinterpret_cast<uint2*>(&XHI[(size_t)node * FH + c8 + epar * 4]) = hp;
        *reinterpret_cast<uint2*>(&XLO[(size_t)node * FH + c8 + epar * 4]) = lp;
    } else {
        const float4 w0 = *reinterpret_cast<const float4*>(&WL[c8]);
        const float4 w1 = *reinterpret_cast<const float4*>(&WL[c8 + 4]);
        float pl = fmaf(o[0], w0.x, fmaf(o[1], w0.y, fmaf(o[2], w0.z, o[3] * w0.w)));
        pl = fmaf(o[4], w1.x, fmaf(o[5], w1.y, fmaf(o[6], w1.z, fmaf(o[7], w1.w, pl))));
#pragma unroll
        for (int off = 16; off >= 1; off >>= 1) pl += __shfl_xor(pl, off);
        if (lane == 0) OUT[node] = pl + BL[0];
    }
}

// ---------------- launch ----------------
extern "C" void kernel_launch(void* const* d_in, const int* in_sizes, int n_in,
                              void* d_out, int out_size, void* d_ws, size_t ws_size,
                              hipStream_t stream) {
    const float* x   = (const float*)d_in[0];
    const int*   ei  = (const int*)d_in[1];
    const float* W1  = (const float*)d_in[2];
    const float* a1s = (const float*)d_in[3];
    const float* a1d = (const float*)d_in[4];
    const float* b1  = (const float*)d_in[5];
    const float* W2  = (const float*)d_in[6];
    const float* a2s = (const float*)d_in[7];
    const float* a2d = (const float*)d_in[8];
    const float* b2  = (const float*)d_in[9];
    const float* Wl  = (const float*)d_in[10];
    const float* bl  = (const float*)d_in[11];
    float* out = (float*)d_out;

    char* w = (char*)d_ws;
    auto alloc = [&](size_t bytes) -> char* {
        char* p = w;
        w += (bytes + 255) & ~size_t(255);
        return p;
    };
    int*   counts = (int*)alloc((size_t)NNODES * 4);
    int*   rp     = (int*)alloc((size_t)(NNODES + 1) * 4);
    int*   cursor = (int*)alloc((size_t)NNODES * 4);
    int*   bsum   = (int*)alloc((size_t)NSB * 4);
    int*   ssrc   = (int*)alloc((size_t)TE * 4);
    ushort_t* hfb = (ushort_t*)alloc((size_t)NNODES * FH * 2);
    // region A: xhi1 (layer1, [N][128]) then x2hi (layer2, [N][256]); region B: lo
    ushort_t* regA = (ushort_t*)alloc((size_t)NNODES * FH * 2);
    ushort_t* regB = (ushort_t*)alloc((size_t)NNODES * FH * 2);
    float* asb    = (float*)alloc((size_t)NNODES * NH * 4);
    float* adb    = (float*)alloc((size_t)NNODES * NH * 4);
    ushort_t* w1th = (ushort_t*)alloc((size_t)128 * 256 * 2);
    ushort_t* w1tl = (ushort_t*)alloc((size_t)128 * 256 * 2);
    ushort_t* w2th = (ushort_t*)alloc((size_t)256 * 256 * 2);
    ushort_t* w2tl = (ushort_t*)alloc((size_t)256 * 256 * 2);

    ushort_t* xhi1 = regA;   // [NNODES][128]
    ushort_t* xlo1 = regB;
    ushort_t* x2hi = regA;   // [NNODES][256] (reuse after gemm1 consumed xhi1)
    ushort_t* x2lo = regB;

    hipMemsetAsync(counts, 0, (size_t)NNODES * 4, stream);
    count_kernel<<<(TE + 255) / 256, 256, 0, stream>>>(ei, counts);
    scan1_kernel<<<NSB, 256, 0, stream>>>(counts, rp, bsum);
    scan2_kernel<<<1, 128, 0, stream>>>(bsum);
    scan3_kernel<<<NSB, 256, 0, stream>>>(rp, bsum, cursor);
    fill_kernel<<<(TE + 255) / 256, 256, 0, stream>>>(ei, cursor, ssrc);

    const int xq = NNODES * 128 / 4;
    split_x_kernel<<<(xq + 255) / 256, 256, 0, stream>>>(x, xhi1, xlo1, xq);
    splitT_w<128><<<128, 256, 0, stream>>>(W1, w1th, w1tl);
    splitT_w<256><<<256, 256, 0, stream>>>(W2, w2th, w2tl);

    const dim3 ggrid((NNODES + 127) / 128, 2);
    gemm_mfma<128><<<ggrid, 256, 0, stream>>>(xhi1, xlo1, w1th, w1tl, a1s, a1d,
                                              hfb, asb, adb);
    aggregate<false><<<NNODES / 4, 256, 0, stream>>>(hfb, asb, adb, rp, ssrc, b1,
                                                     x2hi, x2lo, nullptr, nullptr, nullptr);
    gemm_mfma<256><<<ggrid, 256, 0, stream>>>(x2hi, x2lo, w2th, w2tl, a2s, a2d,
                                              hfb, asb, adb);
    aggregate<true><<<NNODES / 4, 256, 0, stream>>>(hfb, asb, adb, rp, ssrc, b2,
                                                    nullptr, nullptr, Wl, bl, out);
}

// Round 7
// 198.943 us; speedup vs baseline: 2.5244x; 1.0827x over previous
//
#include <hip/hip_runtime.h>
#include <hip/hip_bf16.h>

#define NNODES 30000
#define NEDGES 480000
#define TE (NEDGES + NNODES)   // edges incl. self-loops
#define FH 256                 // hidden width (H*C)
#define NH 8                   // heads
#define NSB ((NNODES + 255) / 256)   // scan blocks = 118

typedef unsigned short ushort_t;
typedef __attribute__((ext_vector_type(8))) _Float16 f16x8;
typedef __attribute__((ext_vector_type(2))) _Float16 f16x2;
typedef __attribute__((ext_vector_type(4))) float f32x4;

// ---------------- CSR build (dst-sorted src lists) ----------------
__global__ void count_kernel(const int* __restrict__ ei, int* __restrict__ counts) {
    int e = blockIdx.x * 256 + threadIdx.x;
    if (e >= TE) return;
    int d = (e < NEDGES) ? ei[NEDGES + e] : (e - NEDGES);
    atomicAdd(&counts[d], 1);
}

// hierarchical scan: (1) per-block local exclusive scan + block sums
__global__ __launch_bounds__(256) void scan1_kernel(const int* __restrict__ counts,
                                                    int* __restrict__ rp,
                                                    int* __restrict__ bsum) {
    __shared__ int s[256];
    const int tid = threadIdx.x;
    const int i = blockIdx.x * 256 + tid;
    int v = (i < NNODES) ? counts[i] : 0;
    s[tid] = v;
    __syncthreads();
    for (int off = 1; off < 256; off <<= 1) {
        int t = (tid >= off) ? s[tid - off] : 0;
        __syncthreads();
        s[tid] += t;
        __syncthreads();
    }
    if (i < NNODES) rp[i] = s[tid] - v;          // local exclusive prefix
    if (tid == 255) bsum[blockIdx.x] = s[255];
}

// (2) scan the 118 block sums in place (exclusive)
__global__ __launch_bounds__(128) void scan2_kernel(int* __restrict__ bsum) {
    __shared__ int s[128];
    const int tid = threadIdx.x;
    int v = (tid < NSB) ? bsum[tid] : 0;
    s[tid] = v;
    __syncthreads();
    for (int off = 1; off < 128; off <<= 1) {
        int t = (tid >= off) ? s[tid - off] : 0;
        __syncthreads();
        s[tid] += t;
        __syncthreads();
    }
    if (tid < NSB) bsum[tid] = s[tid] - v;
}

// (3) add block offsets, fan out to rp/cursor
__global__ __launch_bounds__(256) void scan3_kernel(int* __restrict__ rp,
                                                    const int* __restrict__ bsum,
                                                    int* __restrict__ cursor) {
    const int i = blockIdx.x * 256 + threadIdx.x;
    if (i < NNODES) {
        int r = rp[i] + bsum[blockIdx.x];
        rp[i] = r;
        cursor[i] = r;
    }
    if (i == 0) rp[NNODES] = TE;   // total is a compile-time constant
}

__global__ void fill_kernel(const int* __restrict__ ei, int* __restrict__ cursor,
                            int* __restrict__ ssrc) {
    int e = blockIdx.x * 256 + threadIdx.x;
    if (e >= TE) return;
    int s, d;
    if (e < NEDGES) { s = ei[e]; d = ei[NEDGES + e]; }
    else            { s = e - NEDGES; d = s; }
    int pos = atomicAdd(&cursor[d], 1);
    ssrc[pos] = s;
}

// ---------------- fp16 helpers ----------------
__device__ __forceinline__ float2 h2f2(unsigned u) {   // unpack 2 packed halves
    f16x2 h = __builtin_bit_cast(f16x2, u);
    return make_float2((float)h.x, (float)h.y);
}
__device__ __forceinline__ unsigned f2h2(float a, float b) {  // pack 2 floats
    f16x2 h;
    h.x = (_Float16)a;
    h.y = (_Float16)b;
    return __builtin_bit_cast(unsigned, h);
}

// ---------------- prepass: fp32 -> fp16 ----------------
__global__ void cvt_x_kernel(const float* __restrict__ X,
                             _Float16* __restrict__ out, int nquads) {
    int i = blockIdx.x * 256 + threadIdx.x;
    if (i >= nquads) return;
    float4 v = *reinterpret_cast<const float4*>(&X[(size_t)i * 4]);
    uint2 st;
    st.x = f2h2(v.x, v.y);
    st.y = f2h2(v.z, v.w);
    *reinterpret_cast<uint2*>(&out[(size_t)i * 4]) = st;
}

// W [K][256] row-major -> Wt fp16 [256][K] (n-major)
template<int K>
__global__ void cvtT_w(const float* __restrict__ W, _Float16* __restrict__ t) {
    int idx = blockIdx.x * 256 + threadIdx.x;   // n fast -> coalesced read
    if (idx >= 256 * K) return;
    int n = idx & 255, k = idx >> 8;
    t[n * K + k] = (_Float16)W[idx];
}

// ---------------- fp16 MFMA GEMM (h = X @ W) + fused alpha dots ----------------
// BM=128 x BN=128, BK=32, 256 threads = 4 waves of 64x64 (4x4 frags 16x16x32).
template<int K>
__global__ __launch_bounds__(256) void gemm_mfma(
    const _Float16* __restrict__ A,  const _Float16* __restrict__ Bt,   // [M][K], [256][K]
    const float* __restrict__ ASRC, const float* __restrict__ ADST,
    _Float16* __restrict__ HFh, float* __restrict__ AS, float* __restrict__ AD) {

    constexpr int LDK = 40;   // pad: 80B row stride, 16B aligned chunks
    __shared__ _Float16 Ah[128][LDK], Bh[128][LDK];   // 20 KB total

    const int tid  = threadIdx.x;
    const int lane = tid & 63;
    const int wid  = tid >> 6;
    const int m0 = blockIdx.x * 128;
    const int n0 = blockIdx.y * 128;
    const int wm = (wid & 1) * 64, wn = (wid >> 1) * 64;
    const int q = lane >> 4;          // quarter-wave
    const int c = lane & 15;

    f32x4 acc[4][4];
#pragma unroll
    for (int mi = 0; mi < 4; ++mi)
#pragma unroll
        for (int ni = 0; ni < 4; ++ni) acc[mi][ni] = (f32x4){0.f, 0.f, 0.f, 0.f};

    for (int k0 = 0; k0 < K; k0 += 32) {
        __syncthreads();
#pragma unroll
        for (int rep = 0; rep < 2; ++rep) {
            int idx = tid + 256 * rep;          // 0..511
            int row = idx >> 2;                 // 0..127
            int ch  = (idx & 3) * 8;            // k-chunk of 8 halves
            int gr = m0 + row;
            uint4 v = make_uint4(0u, 0u, 0u, 0u);
            if (gr < NNODES)
                v = *reinterpret_cast<const uint4*>(&A[(size_t)gr * K + k0 + ch]);
            *reinterpret_cast<uint4*>(&Ah[row][ch]) = v;
            uint4 bv = *reinterpret_cast<const uint4*>(&Bt[(size_t)(n0 + row) * K + k0 + ch]);
            *reinterpret_cast<uint4*>(&Bh[row][ch]) = bv;
        }
        __syncthreads();

        const int koff = q * 8;
        f16x8 fa[4], fb[4];
#pragma unroll
        for (int mi = 0; mi < 4; ++mi)
            fa[mi] = *reinterpret_cast<const f16x8*>(&Ah[wm + mi * 16 + c][koff]);
#pragma unroll
        for (int ni = 0; ni < 4; ++ni)
            fb[ni] = *reinterpret_cast<const f16x8*>(&Bh[wn + ni * 16 + c][koff]);
#pragma unroll
        for (int mi = 0; mi < 4; ++mi)
#pragma unroll
            for (int ni = 0; ni < 4; ++ni)
                acc[mi][ni] = __builtin_amdgcn_mfma_f32_16x16x32_f16(fa[mi], fb[ni], acc[mi][ni], 0, 0, 0);
    }

    // ---- epilogue: h (fp16) stores + fused per-head alpha dots (fp32 acc) ----
    float as_v[4], ad_v[4];
#pragma unroll
    for (int ni = 0; ni < 4; ++ni) {
        as_v[ni] = ASRC[n0 + wn + ni * 16 + c];
        ad_v[ni] = ADST[n0 + wn + ni * 16 + c];
    }
    const int head0 = (n0 + wn) >> 5;   // this wave covers heads head0, head0+1

#pragma unroll
    for (int mi = 0; mi < 4; ++mi) {
#pragma unroll
        for (int j = 0; j < 4; ++j) {
            int row = m0 + wm + mi * 16 + q * 4 + j;
            bool ok = row < NNODES;
            if (ok) {
#pragma unroll
                for (int ni = 0; ni < 4; ++ni)
                    HFh[(size_t)row * FH + n0 + wn + ni * 16 + c] = (_Float16)acc[mi][ni][j];
            }
            float ps0 = acc[mi][0][j] * as_v[0] + acc[mi][1][j] * as_v[1];
            float ps1 = acc[mi][2][j] * as_v[2] + acc[mi][3][j] * as_v[3];
            float pd0 = acc[mi][0][j] * ad_v[0] + acc[mi][1][j] * ad_v[1];
            float pd1 = acc[mi][2][j] * ad_v[2] + acc[mi][3][j] * ad_v[3];
#pragma unroll
            for (int off = 8; off >= 1; off >>= 1) {
                ps0 += __shfl_xor(ps0, off);
                ps1 += __shfl_xor(ps1, off);
                pd0 += __shfl_xor(pd0, off);
                pd1 += __shfl_xor(pd1, off);
            }
            if (ok && c == 0) {
                AS[row * NH + head0]     = ps0;
                AS[row * NH + head0 + 1] = ps1;
                AD[row * NH + head0]     = pd0;
                AD[row * NH + head0 + 1] = pd1;
            }
        }
    }
}

// ---------------- Per-node gather aggregation: one WAVE per node ----------------
// fp16 h-rows (512B). Lane owns 8 channels (one 16B load); 32 lanes cover the
// row; the two wave halves process 2 edges in parallel, combined at the end
// with xor-32 shuffles. No LDS, no barriers, no max pass (exp args bounded).
template<bool FINAL>
__global__ __launch_bounds__(256) void aggregate(
    const _Float16* __restrict__ HFh, const float* __restrict__ AS,
    const float* __restrict__ AD,
    const int* __restrict__ rp, const int* __restrict__ ssrc,
    const float* __restrict__ BIAS,
    _Float16* __restrict__ X2H,
    const float* __restrict__ WL, const float* __restrict__ BL,
    float* __restrict__ OUT) {

    const int tid  = threadIdx.x;
    const int lane = tid & 63;
    const int node = __builtin_amdgcn_readfirstlane(blockIdx.x * 4 + (tid >> 6));
    const int epar = lane >> 5;        // which edge of the pair
    const int cg   = lane & 31;        // channel group: owns channels cg*8..cg*8+7
    const int hh   = cg >> 2;          // head of these channels
    const int c8   = cg * 8;

    const float ad = AD[node * NH + hh];
    const int p0   = rp[node];
    const int deg  = rp[node + 1] - p0;   // >= 1 (self-loop)

    float a0=0.f,a1=0.f,a2=0.f,a3=0.f,a4=0.f,a5=0.f,a6=0.f,a7=0.f;
    float den = 0.f;

#pragma unroll 2
    for (int e0 = 0; e0 < deg; e0 += 2) {
        const int  e   = e0 + epar;
        const bool act = e < deg;
        const int  sa  = ssrc[p0 + (act ? e : 0)];
        const float asv = AS[sa * NH + hh];
        const uint4 hv  = *reinterpret_cast<const uint4*>(&HFh[(size_t)sa * FH + c8]);
        float sv = asv + ad;
        sv = sv > 0.f ? sv : 0.2f * sv;
        const float w = act ? __expf(sv) : 0.f;
        den += w;
        float2 c0 = h2f2(hv.x), c1 = h2f2(hv.y), c2 = h2f2(hv.z), c3 = h2f2(hv.w);
        a0 = fmaf(w, c0.x, a0);
        a1 = fmaf(w, c0.y, a1);
        a2 = fmaf(w, c1.x, a2);
        a3 = fmaf(w, c1.y, a3);
        a4 = fmaf(w, c2.x, a4);
        a5 = fmaf(w, c2.y, a5);
        a6 = fmaf(w, c3.x, a6);
        a7 = fmaf(w, c3.y, a7);
    }

    a0 += __shfl_xor(a0, 32); a1 += __shfl_xor(a1, 32);
    a2 += __shfl_xor(a2, 32); a3 += __shfl_xor(a3, 32);
    a4 += __shfl_xor(a4, 32); a5 += __shfl_xor(a5, 32);
    a6 += __shfl_xor(a6, 32); a7 += __shfl_xor(a7, 32);
    den += __shfl_xor(den, 32);

    const float inv = 1.f / (den + 1e-16f);
    const float4 b0 = *reinterpret_cast<const float4*>(&BIAS[c8]);
    const float4 b1 = *reinterpret_cast<const float4*>(&BIAS[c8 + 4]);
    float o[8];
    o[0] = fmaf(a0, inv, b0.x); o[1] = fmaf(a1, inv, b0.y);
    o[2] = fmaf(a2, inv, b0.z); o[3] = fmaf(a3, inv, b0.w);
    o[4] = fmaf(a4, inv, b1.x); o[5] = fmaf(a5, inv, b1.y);
    o[6] = fmaf(a6, inv, b1.z); o[7] = fmaf(a7, inv, b1.w);
#pragma unroll
    for (int j = 0; j < 8; ++j) o[j] = o[j] > 0.f ? o[j] : expm1f(o[j]);

    if (!FINAL) {
        // emit fp16 for the next GEMM (4 channels per half-wave)
        uint2 st;
        st.x = f2h2(o[epar * 4 + 0], o[epar * 4 + 1]);
        st.y = f2h2(o[epar * 4 + 2], o[epar * 4 + 3]);
        *reinterpret_cast<uint2*>(&X2H[(size_t)node * FH + c8 + epar * 4]) = st;
    } else {
        const float4 w0 = *reinterpret_cast<const float4*>(&WL[c8]);
        const float4 w1 = *reinterpret_cast<const float4*>(&WL[c8 + 4]);
        float pl = fmaf(o[0], w0.x, fmaf(o[1], w0.y, fmaf(o[2], w0.z, o[3] * w0.w)));
        pl = fmaf(o[4], w1.x, fmaf(o[5], w1.y, fmaf(o[6], w1.z, fmaf(o[7], w1.w, pl))));
#pragma unroll
        for (int off = 16; off >= 1; off >>= 1) pl += __shfl_xor(pl, off);
        if (lane == 0) OUT[node] = pl + BL[0];
    }
}

// ---------------- launch ----------------
extern "C" void kernel_launch(void* const* d_in, const int* in_sizes, int n_in,
                              void* d_out, int out_size, void* d_ws, size_t ws_size,
                              hipStream_t stream) {
    const float* x   = (const float*)d_in[0];
    const int*   ei  = (const int*)d_in[1];
    const float* W1  = (const float*)d_in[2];
    const float* a1s = (const float*)d_in[3];
    const float* a1d = (const float*)d_in[4];
    const float* b1  = (const float*)d_in[5];
    const float* W2  = (const float*)d_in[6];
    const float* a2s = (const float*)d_in[7];
    const float* a2d = (const float*)d_in[8];
    const float* b2  = (const float*)d_in[9];
    const float* Wl  = (const float*)d_in[10];
    const float* bl  = (const float*)d_in[11];
    float* out = (float*)d_out;

    char* w = (char*)d_ws;
    auto alloc = [&](size_t bytes) -> char* {
        char* p = w;
        w += (bytes + 255) & ~size_t(255);
        return p;
    };
    int*   counts = (int*)alloc((size_t)NNODES * 4);
    int*   rp     = (int*)alloc((size_t)(NNODES + 1) * 4);
    int*   cursor = (int*)alloc((size_t)NNODES * 4);
    int*   bsum   = (int*)alloc((size_t)NSB * 4);
    int*   ssrc   = (int*)alloc((size_t)TE * 4);
    _Float16* hfh = (_Float16*)alloc((size_t)NNODES * FH * 2);
    _Float16* x1h = (_Float16*)alloc((size_t)NNODES * 128 * 2);   // fp16 x (layer-1 A)
    _Float16* x2h = (_Float16*)alloc((size_t)NNODES * FH * 2);    // fp16 layer-2 A
    float* asb    = (float*)alloc((size_t)NNODES * NH * 4);
    float* adb    = (float*)alloc((size_t)NNODES * NH * 4);
    _Float16* w1t = (_Float16*)alloc((size_t)128 * 256 * 2);
    _Float16* w2t = (_Float16*)alloc((size_t)256 * 256 * 2);

    hipMemsetAsync(counts, 0, (size_t)NNODES * 4, stream);
    count_kernel<<<(TE + 255) / 256, 256, 0, stream>>>(ei, counts);
    scan1_kernel<<<NSB, 256, 0, stream>>>(counts, rp, bsum);
    scan2_kernel<<<1, 128, 0, stream>>>(bsum);
    scan3_kernel<<<NSB, 256, 0, stream>>>(rp, bsum, cursor);
    fill_kernel<<<(TE + 255) / 256, 256, 0, stream>>>(ei, cursor, ssrc);

    const int xq = NNODES * 128 / 4;
    cvt_x_kernel<<<(xq + 255) / 256, 256, 0, stream>>>(x, x1h, xq);
    cvtT_w<128><<<128, 256, 0, stream>>>(W1, w1t);
    cvtT_w<256><<<256, 256, 0, stream>>>(W2, w2t);

    const dim3 ggrid((NNODES + 127) / 128, 2);
    gemm_mfma<128><<<ggrid, 256, 0, stream>>>(x1h, w1t, a1s, a1d, hfh, asb, adb);
    aggregate<false><<<NNODES / 4, 256, 0, stream>>>(hfh, asb, adb, rp, ssrc, b1,
                                                     x2h, nullptr, nullptr, nullptr);
    gemm_mfma<256><<<ggrid, 256, 0, stream>>>(x2h, w2t, a2s, a2d, hfh, asb, adb);
    aggregate<true><<<NNODES / 4, 256, 0, stream>>>(hfh, asb, adb, rp, ssrc, b2,
                                                    nullptr, Wl, bl, out);
}